// Round 1
// baseline (237249.121 us; speedup 1.0000x reference)
//
#include <hip/hip_runtime.h>
#include <math.h>

// ---------------------------------------------------------------------------
// LSTM autoencoder, round 0: correctness-first persistent fp32 kernel.
//
// Design:
//  - ONE persistent kernel, 256 WGs x 256 threads. Thread <-> one (b, hid)
//    cell; WG = (b-block of 16) x (hid-block of 16). 256 WGs <= 256 CUs and
//    tiny resource use => all WGs co-resident => hand-rolled global barrier
//    is deadlock-safe (no cooperative launch needed -> graph-capture safe).
//  - Per time step, per layer: gates = bias + x_part + h_prev @ Whh^T, then
//    LSTM cell update. h double-buffered per layer (ping-pong by t parity);
//    c is owner-thread-private between phase transitions.
//  - dec0's input term is constant over time (encoding) -> precomputed once
//    into Gb. Projection (H->16) fused per time step on WGs 0..7.
//  - All math fp32 (exact). MFMA bf16 split-W planned for round 1 once this
//    skeleton is verified.
// ---------------------------------------------------------------------------

#define NB 128   // batch
#define NT 512   // time steps
#define ND 16    // input dim
#define NH 512   // hidden
#define NWG 256
#define NTHR 256

// ws layout in float elements
#define WS_HB   128                    // h[L][p][b][k], L<4, p<2  (barrier words live in [0,128))
#define HSZ     (NB*NH)                // 65536
#define WS_CB   (WS_HB + 8*HSZ)        // c[L][b][k], L<4
#define WS_EB   (WS_CB + 4*HSZ)        // encoding[b][k]
#define WS_GB   (WS_EB + HSZ)          // dec0 const gates [b][g][k]  (NB*4*NH)
// total = 128 + 524288 + 262144 + 65536 + 262144 floats ~= 4.26 MiB

// Global barrier: sense-reversing, agent scope. Safe because all NWG WGs are
// co-resident by construction. cnt is reset by the releaser BEFORE gen is
// released, and no WG can reach the next barrier without observing gen.
__device__ __forceinline__ void gbar(unsigned* cnt, unsigned* gen) {
  __syncthreads();
  if (threadIdx.x == 0) {
    __threadfence();  // publish this WG's plain stores device-wide
    unsigned my = __hip_atomic_load(gen, __ATOMIC_RELAXED, __HIP_MEMORY_SCOPE_AGENT);
    unsigned a  = __hip_atomic_fetch_add(cnt, 1u, __ATOMIC_ACQ_REL, __HIP_MEMORY_SCOPE_AGENT);
    if (a == NWG - 1u) {
      __hip_atomic_store(cnt, 0u, __ATOMIC_RELAXED, __HIP_MEMORY_SCOPE_AGENT);
      __hip_atomic_store(gen, my + 1u, __ATOMIC_RELEASE, __HIP_MEMORY_SCOPE_AGENT);
    } else {
      while (__hip_atomic_load(gen, __ATOMIC_ACQUIRE, __HIP_MEMORY_SCOPE_AGENT) == my)
        __builtin_amdgcn_s_sleep(2);
    }
  }
  __syncthreads();
}

// acc[g] += dot(a[0:K], W[g*gstride + 0:K]) for g=0..3, float4-vectorized.
__device__ __forceinline__ void dot4g(const float* __restrict__ a,
                                      const float* __restrict__ w0,
                                      int gstride, int K, float* __restrict__ acc) {
  const float4* a4 = (const float4*)a;
  const float4* W0 = (const float4*)(w0);
  const float4* W1 = (const float4*)(w0 + gstride);
  const float4* W2 = (const float4*)(w0 + 2 * gstride);
  const float4* W3 = (const float4*)(w0 + 3 * gstride);
  float s0 = 0.f, s1 = 0.f, s2 = 0.f, s3 = 0.f;
  const int n = K >> 2;
#pragma unroll 4
  for (int k = 0; k < n; ++k) {
    float4 av = a4[k];
    float4 w;
    w = W0[k]; s0 += av.x*w.x + av.y*w.y + av.z*w.z + av.w*w.w;
    w = W1[k]; s1 += av.x*w.x + av.y*w.y + av.z*w.z + av.w*w.w;
    w = W2[k]; s2 += av.x*w.x + av.y*w.y + av.z*w.z + av.w*w.w;
    w = W3[k]; s3 += av.x*w.x + av.y*w.y + av.z*w.z + av.w*w.w;
  }
  acc[0] += s0; acc[1] += s1; acc[2] += s2; acc[3] += s3;
}

// torch gate order i,f,g,o (row blocks of NH in the 4H dim)
__device__ __forceinline__ void cell_update(const float* acc, float* ccell, float* hcell) {
  float ig = 1.f / (1.f + __expf(-acc[0]));
  float fg = 1.f / (1.f + __expf(-acc[1]));
  float gg = tanhf(acc[2]);
  float og = 1.f / (1.f + __expf(-acc[3]));
  float c  = fg * (*ccell) + ig * gg;
  *ccell = c;
  *hcell = og * tanhf(c);
}

extern "C" __global__ __launch_bounds__(NTHR)
void lstm_ae_kernel(const float* __restrict__ x,
                    const float* __restrict__ eWih0, const float* __restrict__ eWhh0, const float* __restrict__ eb0,
                    const float* __restrict__ eWih1, const float* __restrict__ eWhh1, const float* __restrict__ eb1,
                    const float* __restrict__ dWih0, const float* __restrict__ dWhh0, const float* __restrict__ db0,
                    const float* __restrict__ dWih1, const float* __restrict__ dWhh1, const float* __restrict__ db1,
                    const float* __restrict__ Wout,  const float* __restrict__ bout,
                    float* __restrict__ out, float* __restrict__ ws) {
  unsigned* cnt = (unsigned*)ws;        // byte 0
  unsigned* gen = (unsigned*)ws + 64;   // byte 256 (separate cacheline)
  float* Hb = ws + WS_HB;
  float* Cb = ws + WS_CB;
  float* Eb = ws + WS_EB;
  float* Gb = ws + WS_GB;

  const int tid = threadIdx.x;
  const int bb = blockIdx.x >> 5;       // 8 b-blocks of 16
  const int hb = blockIdx.x & 31;       // 32 hid-blocks of 16
  const int bi = tid >> 4, hi = tid & 15;
  const int b   = bb * 16 + bi;         // 0..127
  const int hid = hb * 16 + hi;         // 0..511

#define HROW(L, p) (Hb + ((((L) * 2 + (p)) * NB + b) * NH))
#define CCELL(L)   (Cb + ((L) * NB + b) * NH + hid)

  // hoist biases
  const float eb0v[4] = {eb0[hid], eb0[NH + hid], eb0[2 * NH + hid], eb0[3 * NH + hid]};
  const float eb1v[4] = {eb1[hid], eb1[NH + hid], eb1[2 * NH + hid], eb1[3 * NH + hid]};
  const float db1v[4] = {db1[hid], db1[NH + hid], db1[2 * NH + hid], db1[3 * NH + hid]};

  // init: t=0 reads parity-1 buffers; c = 0
  HROW(0, 1)[hid] = 0.f;
  HROW(1, 1)[hid] = 0.f;
  *CCELL(0) = 0.f;
  *CCELL(1) = 0.f;
  gbar(cnt, gen);

  // ---------------- encoder ----------------
  for (int t = 0; t < NT; ++t) {
    const int pw = t & 1, pr = pw ^ 1;
    {  // enc layer 0: K = 16 (x_t) + 512 (h0)
      float acc[4] = {eb0v[0], eb0v[1], eb0v[2], eb0v[3]};
      dot4g(x + (b * NT + t) * ND, eWih0 + hid * ND, NH * ND, ND, acc);
      dot4g(HROW(0, pr), eWhh0 + hid * NH, NH * NH, NH, acc);
      cell_update(acc, CCELL(0), HROW(0, pw) + hid);
    }
    gbar(cnt, gen);
    {  // enc layer 1: K = 512 (y0_t, just produced) + 512 (h1)
      float acc[4] = {eb1v[0], eb1v[1], eb1v[2], eb1v[3]};
      dot4g(HROW(0, pw), eWih1 + hid * NH, NH * NH, NH, acc);
      dot4g(HROW(1, pr), eWhh1 + hid * NH, NH * NH, NH, acc);
      cell_update(acc, CCELL(1), HROW(1, pw) + hid);
    }
    gbar(cnt, gen);
  }

  // ---------------- transition ----------------
  // encoder finals live in parity 1 ((NT-1)&1 == 1). Decoder init = encoder
  // finals per-layer; encoding = final h1 (also output 1).
  {
    float h0f = HROW(0, 1)[hid];
    float h1f = HROW(1, 1)[hid];
    HROW(2, 1)[hid] = h0f;
    HROW(3, 1)[hid] = h1f;
    *CCELL(2) = *CCELL(0);
    *CCELL(3) = *CCELL(1);
    Eb[b * NH + hid] = h1f;
    out[NB * NT * ND + b * NH + hid] = h1f;  // encoding output
  }
  gbar(cnt, gen);
  {  // dec0 input term is time-constant: Gb = db0 + encoding @ dWih0^T
    float acc[4] = {db0[hid], db0[NH + hid], db0[2 * NH + hid], db0[3 * NH + hid]};
    dot4g(Eb + b * NH, dWih0 + hid * NH, NH * NH, NH, acc);
    Gb[(b * 4 + 0) * NH + hid] = acc[0];
    Gb[(b * 4 + 1) * NH + hid] = acc[1];
    Gb[(b * 4 + 2) * NH + hid] = acc[2];
    Gb[(b * 4 + 3) * NH + hid] = acc[3];
  }
  gbar(cnt, gen);

  // ---------------- decoder ----------------
  for (int t = 0; t < NT; ++t) {
    const int pw = t & 1, pr = pw ^ 1;
    {  // dec layer 0: const input part + h2 recurrence
      float acc[4] = {Gb[(b * 4 + 0) * NH + hid], Gb[(b * 4 + 1) * NH + hid],
                      Gb[(b * 4 + 2) * NH + hid], Gb[(b * 4 + 3) * NH + hid]};
      dot4g(HROW(2, pr), dWhh0 + hid * NH, NH * NH, NH, acc);
      cell_update(acc, CCELL(2), HROW(2, pw) + hid);
    }
    gbar(cnt, gen);
    {  // dec layer 1: K = 512 (d0_t) + 512 (h3)
      float acc[4] = {db1v[0], db1v[1], db1v[2], db1v[3]};
      dot4g(HROW(2, pw), dWih1 + hid * NH, NH * NH, NH, acc);
      dot4g(HROW(3, pr), dWhh1 + hid * NH, NH * NH, NH, acc);
      cell_update(acc, CCELL(3), HROW(3, pw) + hid);
    }
    gbar(cnt, gen);
    // projection out[:,t,:] = h3_t @ Wout^T + bout ; 2048 dots on WGs 0..7.
    // Safe: h3[pw] rewritten earliest at t+2, >=3 barriers away.
    if (blockIdx.x < 8) {
      const int p  = blockIdx.x * NTHR + tid;  // 0..2047
      const int pb = p >> 4, pd = p & 15;
      const float* hrow = Hb + (((3 * 2 + pw) * NB + pb) * NH);
      const float4* h4 = (const float4*)hrow;
      const float4* w4 = (const float4*)(Wout + pd * NH);
      float s = bout[pd];
#pragma unroll 4
      for (int k = 0; k < NH / 4; ++k) {
        float4 av = h4[k], wv = w4[k];
        s += av.x * wv.x + av.y * wv.y + av.z * wv.z + av.w * wv.w;
      }
      out[(pb * NT + t) * ND + pd] = s;
    }
  }
#undef HROW
#undef CCELL
}

extern "C" void kernel_launch(void* const* d_in, const int* in_sizes, int n_in,
                              void* d_out, int out_size, void* d_ws, size_t ws_size,
                              hipStream_t stream) {
  const float* xp    = (const float*)d_in[0];
  const float* eWih0 = (const float*)d_in[1];
  const float* eWhh0 = (const float*)d_in[2];
  const float* eb0   = (const float*)d_in[3];
  const float* eWih1 = (const float*)d_in[4];
  const float* eWhh1 = (const float*)d_in[5];
  const float* eb1   = (const float*)d_in[6];
  const float* dWih0 = (const float*)d_in[7];
  const float* dWhh0 = (const float*)d_in[8];
  const float* db0   = (const float*)d_in[9];
  const float* dWih1 = (const float*)d_in[10];
  const float* dWhh1 = (const float*)d_in[11];
  const float* db1   = (const float*)d_in[12];
  const float* Wout  = (const float*)d_in[13];
  const float* bout  = (const float*)d_in[14];

  // barrier words must start at 0 (ws is poisoned 0xAA before every launch)
  hipMemsetAsync(d_ws, 0, 512, stream);
  lstm_ae_kernel<<<NWG, NTHR, 0, stream>>>(
      xp, eWih0, eWhh0, eb0, eWih1, eWhh1, eb1,
      dWih0, dWhh0, db0, dWih1, dWhh1, db1, Wout, bout,
      (float*)d_out, (float*)d_ws);
}

// Round 2
// 56669.263 us; speedup vs baseline: 4.1866x; 4.1866x over previous
//
#include <hip/hip_runtime.h>
#include <math.h>

// ---------------------------------------------------------------------------
// Round 1: persistent-RNN MFMA kernel.
//  - 256 WGs x 256 thr (4 waves). WG <-> (b-block 16) x (hid-block 16), owns
//    all 4 gates for its cells. Weights held in VGPRs as bf16 hi/lo fragment
//    pairs (bf16x3 emulated-fp32 MFMA: hi*hi + hi*lo + lo*hi).
//  - Split-K over the 4 waves; partials reduced via 16KB LDS; LSTM cell
//    update fused in fp32 (c stays in thread registers for all 4 layers).
//  - h stored in ws as chunk-tiled bf16 hi/lo planes (double-buffered by t
//    parity) so A-fragment loads are coalesced 1KB/wave global reads.
//  - x-term (K=16) and output projection kept in exact fp32 VALU.
//  - Round-0 global barrier reused verbatim (proven on HW).
// ---------------------------------------------------------------------------

#define NB 128
#define NT 512
#define ND 16
#define NH 512
#define NWG 256
#define NTHR 256

typedef __attribute__((ext_vector_type(8))) short short8;
typedef __attribute__((ext_vector_type(4))) float float4v;

// ws byte layout:
//  [0,512)          barrier cnt @0, gen @256
//  [512, 512+2MB)   16 h-planes: (L in 0..3) x (parity) x (hi/lo), each
//                   128KB, chunk-tiled: elem(b,k) at (k>>5)*8192 + b*64 + (k&31)*2
//  [+2MB, +2MB+256KB) h3 fp32 plane [b][k] for the projection
#define PLANE_BYTES (NB * NH * 2)          // 131072
#define AH_PLANE(wsB, L, par, hl) ((wsB) + 512 + (size_t)(((L) * 2 + (par)) * 2 + (hl)) * PLANE_BYTES)
#define H3F_PTR(wsB) ((float*)((wsB) + 512 + 16 * (size_t)PLANE_BYTES))

__device__ __forceinline__ void gbar(unsigned* cnt, unsigned* gen) {
  __syncthreads();
  if (threadIdx.x == 0) {
    __threadfence();
    unsigned my = __hip_atomic_load(gen, __ATOMIC_RELAXED, __HIP_MEMORY_SCOPE_AGENT);
    unsigned a  = __hip_atomic_fetch_add(cnt, 1u, __ATOMIC_ACQ_REL, __HIP_MEMORY_SCOPE_AGENT);
    if (a == NWG - 1u) {
      __hip_atomic_store(cnt, 0u, __ATOMIC_RELAXED, __HIP_MEMORY_SCOPE_AGENT);
      __hip_atomic_store(gen, my + 1u, __ATOMIC_RELEASE, __HIP_MEMORY_SCOPE_AGENT);
    } else {
      while (__hip_atomic_load(gen, __ATOMIC_ACQUIRE, __HIP_MEMORY_SCOPE_AGENT) == my)
        __builtin_amdgcn_s_sleep(2);
    }
  }
  __syncthreads();
}

__device__ __forceinline__ unsigned short f2bf(float f) {
  union { float f; unsigned u; } v; v.f = f;
  unsigned r = v.u + 0x7fffu + ((v.u >> 16) & 1u);  // RNE
  return (unsigned short)(r >> 16);
}
__device__ __forceinline__ float bf2f(unsigned short u) {
  union { float f; unsigned u; } v; v.u = ((unsigned)u) << 16; return v.f;
}
__device__ __forceinline__ void split2(float f, unsigned short& hi, unsigned short& lo) {
  hi = f2bf(f);
  lo = f2bf(f - bf2f(hi));
}

// load one 8-wide W fragment (8 consecutive fp32) -> bf16 hi/lo short8
__device__ __forceinline__ void load_wfrag(const float* __restrict__ p, short8& h, short8& l) {
#pragma unroll
  for (int j = 0; j < 8; ++j) {
    unsigned short a, b2; split2(p[j], a, b2);
    h[j] = (short)a; l[j] = (short)b2;
  }
}

// layer0-style frags: single (2048 x 512) W, 4 chunks per wave (split-K/4)
__device__ __forceinline__ void load_frags_single(const float* __restrict__ W, int w, int hb, int lane,
                                                  short8 (&fh)[4][4], short8 (&fl)[4][4]) {
  const int ln = lane & 15, lq = lane >> 4;
#pragma unroll
  for (int cc = 0; cc < 4; ++cc) {
    const int k = (w * 4 + cc) * 32 + lq * 8;
#pragma unroll
    for (int g = 0; g < 4; ++g) {
      const float* p = W + (size_t)(g * NH + hb * 16 + ln) * NH + k;
      load_wfrag(p, fh[cc][g], fl[cc][g]);
    }
  }
}

// layer1-style frags: concat [Wa | Wb] along K (each 2048 x 512), 8 chunks/wave
__device__ __forceinline__ void load_frags_concat(const float* __restrict__ Wa, const float* __restrict__ Wb,
                                                  int w, int hb, int lane,
                                                  short8 (&fh)[8][4], short8 (&fl)[8][4]) {
  const int ln = lane & 15, lq = lane >> 4;
#pragma unroll
  for (int cc = 0; cc < 8; ++cc) {
    const int k = (w * 8 + cc) * 32 + lq * 8;
    const float* W = (k < 512) ? Wa : Wb;
    const int kk = (k < 512) ? k : k - 512;
#pragma unroll
    for (int g = 0; g < 4; ++g) {
      const float* p = W + (size_t)(g * NH + hb * 16 + ln) * NH + kk;
      load_wfrag(p, fh[cc][g], fl[cc][g]);
    }
  }
}

// K-slice GEMM: NCH chunks from one (hi,lo) plane pair starting at chunk c0.
template <int NCH>
__device__ __forceinline__ void gemm_acc(const char* __restrict__ pHi, const char* __restrict__ pLo,
                                         int c0, int aoff,
                                         const short8 (&wh)[NCH][4], const short8 (&wl)[NCH][4],
                                         float4v (&acc)[4]) {
#pragma unroll
  for (int cc = 0; cc < NCH; ++cc) {
    const short8 ah = *(const short8*)(pHi + (size_t)(c0 + cc) * 8192 + aoff);
    const short8 al = *(const short8*)(pLo + (size_t)(c0 + cc) * 8192 + aoff);
#pragma unroll
    for (int g = 0; g < 4; ++g) {
      acc[g] = __builtin_amdgcn_mfma_f32_16x16x32_bf16(ah, wh[cc][g], acc[g], 0, 0, 0);
      acc[g] = __builtin_amdgcn_mfma_f32_16x16x32_bf16(ah, wl[cc][g], acc[g], 0, 0, 0);
      acc[g] = __builtin_amdgcn_mfma_f32_16x16x32_bf16(al, wh[cc][g], acc[g], 0, 0, 0);
    }
  }
}

__device__ __forceinline__ void write_red(float* __restrict__ red, int w, int lane, const float4v (&acc)[4]) {
  const int ln = lane & 15, lq = lane >> 4;
#pragma unroll
  for (int g = 0; g < 4; ++g)
#pragma unroll
    for (int r = 0; r < 4; ++r)
      red[((w * 4 + g) * 16 + (lq * 4 + r)) * 16 + ln] = acc[g][r];
}

__device__ __forceinline__ void store_h(char* __restrict__ pHi, char* __restrict__ pLo, int b, int hid, float h) {
  unsigned short hi, lo; split2(h, hi, lo);
  const size_t off = (size_t)(hid >> 5) * 8192 + (size_t)b * 64 + (size_t)(hid & 31) * 2;
  *(unsigned short*)(pHi + off) = hi;
  *(unsigned short*)(pLo + off) = lo;
}

__device__ __forceinline__ float sigf(float v) { return 1.f / (1.f + __expf(-v)); }

extern "C" __global__ __launch_bounds__(NTHR, 1)
void lstm_ae_kernel(const float* __restrict__ x,
                    const float* __restrict__ eWih0, const float* __restrict__ eWhh0, const float* __restrict__ eb0,
                    const float* __restrict__ eWih1, const float* __restrict__ eWhh1, const float* __restrict__ eb1,
                    const float* __restrict__ dWih0, const float* __restrict__ dWhh0, const float* __restrict__ db0,
                    const float* __restrict__ dWih1, const float* __restrict__ dWhh1, const float* __restrict__ db1,
                    const float* __restrict__ Wout,  const float* __restrict__ bout,
                    float* __restrict__ out, char* __restrict__ wsB) {
  __shared__ float red[4 * 4 * 16 * 16];  // [w][g][m][n] = 16KB

  unsigned* cnt = (unsigned*)wsB;
  unsigned* gen = (unsigned*)(wsB + 256);
  float* H3F = H3F_PTR(wsB);

  const int tid  = threadIdx.x;
  const int lane = tid & 63;
  const int w    = tid >> 6;           // wave id 0..3
  const int bb   = blockIdx.x >> 5;    // 8 b-blocks
  const int hb   = blockIdx.x & 31;    // 32 hid-blocks
  const int b0   = bb * 16;
  const int ln   = lane & 15, lq = lane >> 4;
  const int aoff = (b0 + ln) * 64 + lq * 16;   // byte offset of this lane's a-frag within a chunk
  const int bi = tid >> 4, hi_ = tid & 15;     // cell ids (256 threads = 256 cells)
  const int b = b0 + bi, hid = hb * 16 + hi_;

  // ---- prologue: zero parity-1 planes of L0/L1, zero c, hoist biases ----
  store_h(AH_PLANE(wsB, 0, 1, 0), AH_PLANE(wsB, 0, 1, 1), b, hid, 0.f);
  store_h(AH_PLANE(wsB, 1, 1, 0), AH_PLANE(wsB, 1, 1, 1), b, hid, 0.f);
  float c0 = 0.f, c1 = 0.f, c2 = 0.f, c3 = 0.f;

  const float eb0v[4] = {eb0[hid], eb0[NH + hid], eb0[2 * NH + hid], eb0[3 * NH + hid]};
  const float eb1v[4] = {eb1[hid], eb1[NH + hid], eb1[2 * NH + hid], eb1[3 * NH + hid]};
  const float db1v[4] = {db1[hid], db1[NH + hid], db1[2 * NH + hid], db1[3 * NH + hid]};

  // ---- encoder weight fragments into VGPRs ----
  short8 w0h[4][4], w0l[4][4];   // K=512 slot
  short8 w1h[8][4], w1l[8][4];   // K=1024 slot
  load_frags_single(eWhh0, w, hb, lane, w0h, w0l);
  load_frags_concat(eWih1, eWhh1, w, hb, lane, w1h, w1l);

  const float4v zacc = {0.f, 0.f, 0.f, 0.f};
  gbar(cnt, gen);

  float h0fin = 0.f, h1fin = 0.f;

  // ======================= encoder =======================
  for (int t = 0; t < NT; ++t) {
    const int pw = t & 1, pr = pw ^ 1;
    {  // enc0: gates = eb0 + x_t@Wih0^T (fp32 epilogue) + h0@Whh0^T (MFMA)
      float4v acc[4] = {zacc, zacc, zacc, zacc};
      gemm_acc<4>(AH_PLANE(wsB, 0, pr, 0), AH_PLANE(wsB, 0, pr, 1), w * 4, aoff, w0h, w0l, acc);
      write_red(red, w, lane, acc);
      __syncthreads();
      float s[4];
#pragma unroll
      for (int g = 0; g < 4; ++g) {
        float v = eb0v[g];
#pragma unroll
        for (int ww = 0; ww < 4; ++ww) v += red[((ww * 4 + g) * 16 + bi) * 16 + hi_];
        s[g] = v;
      }
      // exact fp32 x-term (K=16)
      const float* xr = x + ((size_t)b * NT + t) * ND;
      float xv[16];
#pragma unroll
      for (int j = 0; j < 16; ++j) xv[j] = xr[j];
#pragma unroll
      for (int g = 0; g < 4; ++g) {
        const float* wr = eWih0 + (size_t)(g * NH + hid) * ND;
        float v = 0.f;
#pragma unroll
        for (int j = 0; j < 16; ++j) v += xv[j] * wr[j];
        s[g] += v;
      }
      float ig = sigf(s[0]), fg = sigf(s[1]), gg = tanhf(s[2]), og = sigf(s[3]);
      c0 = fg * c0 + ig * gg;
      float h = og * tanhf(c0);
      store_h(AH_PLANE(wsB, 0, pw, 0), AH_PLANE(wsB, 0, pw, 1), b, hid, h);
      if (t == NT - 1) h0fin = h;
    }
    gbar(cnt, gen);
    {  // enc1: A = [h0_new | h1_prev], K=1024
      float4v acc[4] = {zacc, zacc, zacc, zacc};
      const int half = (w < 2);
      const char* pH = half ? AH_PLANE(wsB, 0, pw, 0) : AH_PLANE(wsB, 1, pr, 0);
      const char* pL = half ? AH_PLANE(wsB, 0, pw, 1) : AH_PLANE(wsB, 1, pr, 1);
      const int c0i = half ? w * 8 : (w - 2) * 8;
      gemm_acc<8>(pH, pL, c0i, aoff, w1h, w1l, acc);
      write_red(red, w, lane, acc);
      __syncthreads();
      float s[4];
#pragma unroll
      for (int g = 0; g < 4; ++g) {
        float v = eb1v[g];
#pragma unroll
        for (int ww = 0; ww < 4; ++ww) v += red[((ww * 4 + g) * 16 + bi) * 16 + hi_];
        s[g] = v;
      }
      float ig = sigf(s[0]), fg = sigf(s[1]), gg = tanhf(s[2]), og = sigf(s[3]);
      c1 = fg * c1 + ig * gg;
      float h = og * tanhf(c1);
      store_h(AH_PLANE(wsB, 1, pw, 0), AH_PLANE(wsB, 1, pw, 1), b, hid, h);
      if (t == NT - 1) h1fin = h;
    }
    gbar(cnt, gen);
  }

  // ======================= transition =======================
  out[(size_t)NB * NT * ND + (size_t)b * NH + hid] = h1fin;   // encoding output
  c2 = c0; c3 = c1;
  store_h(AH_PLANE(wsB, 2, 1, 0), AH_PLANE(wsB, 2, 1, 1), b, hid, h0fin);
  store_h(AH_PLANE(wsB, 3, 1, 0), AH_PLANE(wsB, 3, 1, 1), b, hid, h1fin);

  // Gb = db0 + encoding @ dWih0^T via one MFMA pass (A = h1 plane par1)
  float Gbreg[4];
  load_frags_single(dWih0, w, hb, lane, w0h, w0l);
  {
    float4v acc[4] = {zacc, zacc, zacc, zacc};
    gemm_acc<4>(AH_PLANE(wsB, 1, 1, 0), AH_PLANE(wsB, 1, 1, 1), w * 4, aoff, w0h, w0l, acc);
    write_red(red, w, lane, acc);
    __syncthreads();
#pragma unroll
    for (int g = 0; g < 4; ++g) {
      float v = db0[g * NH + hid];
#pragma unroll
      for (int ww = 0; ww < 4; ++ww) v += red[((ww * 4 + g) * 16 + bi) * 16 + hi_];
      Gbreg[g] = v;
    }
  }
  // decoder weights into the fragment registers
  load_frags_single(dWhh0, w, hb, lane, w0h, w0l);
  load_frags_concat(dWih1, dWhh1, w, hb, lane, w1h, w1l);
  gbar(cnt, gen);  // publishes L2/L3 par-1 planes

  // ======================= decoder =======================
  for (int t = 0; t < NT; ++t) {
    const int pw = t & 1, pr = pw ^ 1;
    {  // dec0: gates = Gb + h2@dWhh0^T
      float4v acc[4] = {zacc, zacc, zacc, zacc};
      gemm_acc<4>(AH_PLANE(wsB, 2, pr, 0), AH_PLANE(wsB, 2, pr, 1), w * 4, aoff, w0h, w0l, acc);
      write_red(red, w, lane, acc);
      __syncthreads();
      float s[4];
#pragma unroll
      for (int g = 0; g < 4; ++g) {
        float v = Gbreg[g];
#pragma unroll
        for (int ww = 0; ww < 4; ++ww) v += red[((ww * 4 + g) * 16 + bi) * 16 + hi_];
        s[g] = v;
      }
      float ig = sigf(s[0]), fg = sigf(s[1]), gg = tanhf(s[2]), og = sigf(s[3]);
      c2 = fg * c2 + ig * gg;
      float h = og * tanhf(c2);
      store_h(AH_PLANE(wsB, 2, pw, 0), AH_PLANE(wsB, 2, pw, 1), b, hid, h);
    }
    gbar(cnt, gen);
    {  // dec1: A = [h2_new | h3_prev], K=1024
      float4v acc[4] = {zacc, zacc, zacc, zacc};
      const int half = (w < 2);
      const char* pH = half ? AH_PLANE(wsB, 2, pw, 0) : AH_PLANE(wsB, 3, pr, 0);
      const char* pL = half ? AH_PLANE(wsB, 2, pw, 1) : AH_PLANE(wsB, 3, pr, 1);
      const int c0i = half ? w * 8 : (w - 2) * 8;
      gemm_acc<8>(pH, pL, c0i, aoff, w1h, w1l, acc);
      write_red(red, w, lane, acc);
      __syncthreads();
      float s[4];
#pragma unroll
      for (int g = 0; g < 4; ++g) {
        float v = db1v[g];
#pragma unroll
        for (int ww = 0; ww < 4; ++ww) v += red[((ww * 4 + g) * 16 + bi) * 16 + hi_];
        s[g] = v;
      }
      float ig = sigf(s[0]), fg = sigf(s[1]), gg = tanhf(s[2]), og = sigf(s[3]);
      c3 = fg * c3 + ig * gg;
      float h = og * tanhf(c3);
      store_h(AH_PLANE(wsB, 3, pw, 0), AH_PLANE(wsB, 3, pw, 1), b, hid, h);
      H3F[(size_t)b * NH + hid] = h;   // exact fp32 for the projection
    }
    gbar(cnt, gen);
    {  // projection: 2048 dots (K=512); 8 per WG, 2 per wave, wave-parallel.
      // H3F(t) is stable until dec1(t+1), which is >=1 barrier away.
      int idx = blockIdx.x * 8 + w * 2;
#pragma unroll
      for (int rep = 0; rep < 2; ++rep, ++idx) {
        const int pb = idx >> 4, pd = idx & 15;
        const float* hr = H3F + (size_t)pb * NH + lane * 8;
        const float* wr = Wout + (size_t)pd * NH + lane * 8;
        float ssum = 0.f;
#pragma unroll
        for (int j = 0; j < 8; ++j) ssum += hr[j] * wr[j];
#pragma unroll
        for (int off = 32; off >= 1; off >>= 1) ssum += __shfl_xor(ssum, off, 64);
        if (lane == 0) out[((size_t)pb * NT + t) * ND + pd] = ssum + bout[pd];
      }
    }
  }
}

extern "C" void kernel_launch(void* const* d_in, const int* in_sizes, int n_in,
                              void* d_out, int out_size, void* d_ws, size_t ws_size,
                              hipStream_t stream) {
  const float* xp    = (const float*)d_in[0];
  const float* eWih0 = (const float*)d_in[1];
  const float* eWhh0 = (const float*)d_in[2];
  const float* eb0   = (const float*)d_in[3];
  const float* eWih1 = (const float*)d_in[4];
  const float* eWhh1 = (const float*)d_in[5];
  const float* eb1   = (const float*)d_in[6];
  const float* dWih0 = (const float*)d_in[7];
  const float* dWhh0 = (const float*)d_in[8];
  const float* db0   = (const float*)d_in[9];
  const float* dWih1 = (const float*)d_in[10];
  const float* dWhh1 = (const float*)d_in[11];
  const float* db1   = (const float*)d_in[12];
  const float* Wout  = (const float*)d_in[13];
  const float* bout  = (const float*)d_in[14];

  hipMemsetAsync(d_ws, 0, 512, stream);  // barrier words
  lstm_ae_kernel<<<NWG, NTHR, 0, stream>>>(
      xp, eWih0, eWhh0, eb0, eWih1, eWhh1, eb1,
      dWih0, dWhh0, db0, dWih1, dWhh1, db1, Wout, bout,
      (float*)d_out, (char*)d_ws);
}

// Round 3
// 29462.326 us; speedup vs baseline: 8.0526x; 1.9234x over previous
//
#include <hip/hip_runtime.h>
#include <math.h>

// ---------------------------------------------------------------------------
// Round 2: per-b-block group barriers (8 x 32 WGs) + layer software-pipelining
// (enc0(t) || enc1(t-1) per interval -> 1 barrier/interval instead of 2).
// Compute core (bf16x3 MFMA, VGPR-resident weights, split-K LDS reduction)
// carried verbatim from the passing round-1 kernel.
//  - group = blockIdx & 7 (b-block). Round-robin dispatch puts a group's 32
//    WGs on one XCD (heuristic only; correctness is placement-independent
//    because barrier atomics are device-scope).
//  - Each group's h-planes rows touch distinct 1KB blocks -> no false sharing.
// ---------------------------------------------------------------------------

#define NB 128
#define NT 512
#define ND 16
#define NH 512
#define NWG 256
#define NTHR 256
#define NGRP 8
#define GWG 32   // WGs per group barrier

typedef __attribute__((ext_vector_type(8))) short short8;
typedef __attribute__((ext_vector_type(4))) float float4v;

// ws layout:
//  [0, 8192)                     8 group barriers, 1KB apart (cnt @+0, gen @+256)
//  [8192, 8192+2MB)              16 h-planes (L, parity, hi/lo) 128KB each,
//                                chunk-tiled: elem(b,k) at (k>>5)*8192 + b*64 + (k&31)*2
//  [+2MB, +2MB+512KB)            H3F fp32 planes [par][b][k] for the projection
#define PLANE_BYTES (NB * NH * 2)
#define BAR_BYTES 8192
#define AH_PLANE(wsB, L, par, hl) ((wsB) + BAR_BYTES + (size_t)(((L) * 2 + (par)) * 2 + (hl)) * PLANE_BYTES)
#define H3F_PTR(wsB, par) ((float*)((wsB) + BAR_BYTES + 16 * (size_t)PLANE_BYTES + (size_t)(par) * NB * NH * 4))

__device__ __forceinline__ void gbar(unsigned* cnt, unsigned* gen) {
  __syncthreads();
  if (threadIdx.x == 0) {
    __threadfence();
    unsigned my = __hip_atomic_load(gen, __ATOMIC_RELAXED, __HIP_MEMORY_SCOPE_AGENT);
    unsigned a  = __hip_atomic_fetch_add(cnt, 1u, __ATOMIC_ACQ_REL, __HIP_MEMORY_SCOPE_AGENT);
    if (a == GWG - 1u) {
      __hip_atomic_store(cnt, 0u, __ATOMIC_RELAXED, __HIP_MEMORY_SCOPE_AGENT);
      __hip_atomic_store(gen, my + 1u, __ATOMIC_RELEASE, __HIP_MEMORY_SCOPE_AGENT);
    } else {
      while (__hip_atomic_load(gen, __ATOMIC_ACQUIRE, __HIP_MEMORY_SCOPE_AGENT) == my)
        __builtin_amdgcn_s_sleep(1);
    }
  }
  __syncthreads();
}

__device__ __forceinline__ unsigned short f2bf(float f) {
  union { float f; unsigned u; } v; v.f = f;
  unsigned r = v.u + 0x7fffu + ((v.u >> 16) & 1u);  // RNE
  return (unsigned short)(r >> 16);
}
__device__ __forceinline__ float bf2f(unsigned short u) {
  union { float f; unsigned u; } v; v.u = ((unsigned)u) << 16; return v.f;
}
__device__ __forceinline__ void split2(float f, unsigned short& hi, unsigned short& lo) {
  hi = f2bf(f);
  lo = f2bf(f - bf2f(hi));
}

__device__ __forceinline__ void load_wfrag(const float* __restrict__ p, short8& h, short8& l) {
#pragma unroll
  for (int j = 0; j < 8; ++j) {
    unsigned short a, b2; split2(p[j], a, b2);
    h[j] = (short)a; l[j] = (short)b2;
  }
}

__device__ __forceinline__ void load_frags_single(const float* __restrict__ W, int w, int hb, int lane,
                                                  short8 (&fh)[4][4], short8 (&fl)[4][4]) {
  const int ln = lane & 15, lq = lane >> 4;
#pragma unroll
  for (int cc = 0; cc < 4; ++cc) {
    const int k = (w * 4 + cc) * 32 + lq * 8;
#pragma unroll
    for (int g = 0; g < 4; ++g) {
      const float* p = W + (size_t)(g * NH + hb * 16 + ln) * NH + k;
      load_wfrag(p, fh[cc][g], fl[cc][g]);
    }
  }
}

__device__ __forceinline__ void load_frags_concat(const float* __restrict__ Wa, const float* __restrict__ Wb,
                                                  int w, int hb, int lane,
                                                  short8 (&fh)[8][4], short8 (&fl)[8][4]) {
  const int ln = lane & 15, lq = lane >> 4;
#pragma unroll
  for (int cc = 0; cc < 8; ++cc) {
    const int k = (w * 8 + cc) * 32 + lq * 8;
    const float* W = (k < 512) ? Wa : Wb;
    const int kk = (k < 512) ? k : k - 512;
#pragma unroll
    for (int g = 0; g < 4; ++g) {
      const float* p = W + (size_t)(g * NH + hb * 16 + ln) * NH + kk;
      load_wfrag(p, fh[cc][g], fl[cc][g]);
    }
  }
}

template <int NCH>
__device__ __forceinline__ void gemm_acc(const char* __restrict__ pHi, const char* __restrict__ pLo,
                                         int c0, int aoff,
                                         const short8 (&wh)[NCH][4], const short8 (&wl)[NCH][4],
                                         float4v (&acc)[4]) {
#pragma unroll
  for (int cc = 0; cc < NCH; ++cc) {
    const short8 ah = *(const short8*)(pHi + (size_t)(c0 + cc) * 8192 + aoff);
    const short8 al = *(const short8*)(pLo + (size_t)(c0 + cc) * 8192 + aoff);
#pragma unroll
    for (int g = 0; g < 4; ++g) {
      acc[g] = __builtin_amdgcn_mfma_f32_16x16x32_bf16(ah, wh[cc][g], acc[g], 0, 0, 0);
      acc[g] = __builtin_amdgcn_mfma_f32_16x16x32_bf16(ah, wl[cc][g], acc[g], 0, 0, 0);
      acc[g] = __builtin_amdgcn_mfma_f32_16x16x32_bf16(al, wh[cc][g], acc[g], 0, 0, 0);
    }
  }
}

__device__ __forceinline__ void write_red(float* __restrict__ red, int w, int lane, const float4v (&acc)[4]) {
  const int ln = lane & 15, lq = lane >> 4;
#pragma unroll
  for (int g = 0; g < 4; ++g)
#pragma unroll
    for (int r = 0; r < 4; ++r)
      red[((w * 4 + g) * 16 + (lq * 4 + r)) * 16 + ln] = acc[g][r];
}

__device__ __forceinline__ void store_h(char* __restrict__ pHi, char* __restrict__ pLo, int b, int hid, float h) {
  unsigned short hi, lo; split2(h, hi, lo);
  const size_t off = (size_t)(hid >> 5) * 8192 + (size_t)b * 64 + (size_t)(hid & 31) * 2;
  *(unsigned short*)(pHi + off) = hi;
  *(unsigned short*)(pLo + off) = lo;
}

__device__ __forceinline__ float sigf(float v) { return 1.f / (1.f + __expf(-v)); }

extern "C" __global__ __launch_bounds__(NTHR, 1)
void lstm_ae_kernel(const float* __restrict__ x,
                    const float* __restrict__ eWih0, const float* __restrict__ eWhh0, const float* __restrict__ eb0,
                    const float* __restrict__ eWih1, const float* __restrict__ eWhh1, const float* __restrict__ eb1,
                    const float* __restrict__ dWih0, const float* __restrict__ dWhh0, const float* __restrict__ db0,
                    const float* __restrict__ dWih1, const float* __restrict__ dWhh1, const float* __restrict__ db1,
                    const float* __restrict__ Wout,  const float* __restrict__ bout,
                    float* __restrict__ out, char* __restrict__ wsB) {
  __shared__ float red[4 * 4 * 16 * 16];  // 16KB

  const int grp = blockIdx.x & 7;        // b-block == barrier group (XCD-affine)
  const int hb  = blockIdx.x >> 3;       // 0..31 hid-block
  unsigned* cnt = (unsigned*)(wsB + (size_t)grp * 1024);
  unsigned* gen = (unsigned*)(wsB + (size_t)grp * 1024 + 256);

  const int tid  = threadIdx.x;
  const int lane = tid & 63;
  const int w    = tid >> 6;
  const int b0   = grp * 16;
  const int ln   = lane & 15, lq = lane >> 4;
  const int aoff = (b0 + ln) * 64 + lq * 16;
  const int bi = tid >> 4, hi_ = tid & 15;
  const int b = b0 + bi, hid = hb * 16 + hi_;

  // ---- prologue ----
  store_h(AH_PLANE(wsB, 0, 1, 0), AH_PLANE(wsB, 0, 1, 1), b, hid, 0.f);
  store_h(AH_PLANE(wsB, 1, 1, 0), AH_PLANE(wsB, 1, 1, 1), b, hid, 0.f);
  float c0 = 0.f, c1 = 0.f, c2 = 0.f, c3 = 0.f;

  const float eb0v[4] = {eb0[hid], eb0[NH + hid], eb0[2 * NH + hid], eb0[3 * NH + hid]};
  const float eb1v[4] = {eb1[hid], eb1[NH + hid], eb1[2 * NH + hid], eb1[3 * NH + hid]};
  const float db1v[4] = {db1[hid], db1[NH + hid], db1[2 * NH + hid], db1[3 * NH + hid]};

  short8 w0h[4][4], w0l[4][4];
  short8 w1h[8][4], w1l[8][4];
  load_frags_single(eWhh0, w, hb, lane, w0h, w0l);
  load_frags_concat(eWih1, eWhh1, w, hb, lane, w1h, w1l);

  const float4v zacc = {0.f, 0.f, 0.f, 0.f};
  gbar(cnt, gen);

  float h0fin = 0.f, h1fin = 0.f;

  // ============ encoder: interval i does enc0(t=i) || enc1(t=i-1) ============
  for (int i = 0; i <= NT; ++i) {
    if (i < NT) {  // enc0(t=i): reads h0(i-1) @ par (i&1)^1, writes h0(i) @ par i&1
      const int pr = (i & 1) ^ 1;
      float4v acc[4] = {zacc, zacc, zacc, zacc};
      gemm_acc<4>(AH_PLANE(wsB, 0, pr, 0), AH_PLANE(wsB, 0, pr, 1), w * 4, aoff, w0h, w0l, acc);
      write_red(red, w, lane, acc);
      __syncthreads();
      float s[4];
#pragma unroll
      for (int g = 0; g < 4; ++g) {
        float v = eb0v[g];
#pragma unroll
        for (int ww = 0; ww < 4; ++ww) v += red[((ww * 4 + g) * 16 + bi) * 16 + hi_];
        s[g] = v;
      }
      const float* xr = x + ((size_t)b * NT + i) * ND;
      float xv[16];
#pragma unroll
      for (int j = 0; j < 16; ++j) xv[j] = xr[j];
#pragma unroll
      for (int g = 0; g < 4; ++g) {
        const float* wr = eWih0 + (size_t)(g * NH + hid) * ND;
        float v = 0.f;
#pragma unroll
        for (int j = 0; j < 16; ++j) v += xv[j] * wr[j];
        s[g] += v;
      }
      float ig = sigf(s[0]), fg = sigf(s[1]), gg = tanhf(s[2]), og = sigf(s[3]);
      c0 = fg * c0 + ig * gg;
      float h = og * tanhf(c0);
      store_h(AH_PLANE(wsB, 0, i & 1, 0), AH_PLANE(wsB, 0, i & 1, 1), b, hid, h);
      if (i == NT - 1) h0fin = h;
    }
    __syncthreads();  // red reuse fence between the two phases
    if (i >= 1) {  // enc1(te=i-1): A=[h0(te) @ par te&1 | h1(te-1) @ par (te&1)^1]
      const int te = i - 1;
      const int pA = te & 1, pB = pA ^ 1;
      float4v acc[4] = {zacc, zacc, zacc, zacc};
      const int half = (w < 2);
      const char* pH = half ? AH_PLANE(wsB, 0, pA, 0) : AH_PLANE(wsB, 1, pB, 0);
      const char* pL = half ? AH_PLANE(wsB, 0, pA, 1) : AH_PLANE(wsB, 1, pB, 1);
      const int c0i = half ? w * 8 : (w - 2) * 8;
      gemm_acc<8>(pH, pL, c0i, aoff, w1h, w1l, acc);
      write_red(red, w, lane, acc);
      __syncthreads();
      float s[4];
#pragma unroll
      for (int g = 0; g < 4; ++g) {
        float v = eb1v[g];
#pragma unroll
        for (int ww = 0; ww < 4; ++ww) v += red[((ww * 4 + g) * 16 + bi) * 16 + hi_];
        s[g] = v;
      }
      float ig = sigf(s[0]), fg = sigf(s[1]), gg = tanhf(s[2]), og = sigf(s[3]);
      c1 = fg * c1 + ig * gg;
      float h = og * tanhf(c1);
      store_h(AH_PLANE(wsB, 1, te & 1, 0), AH_PLANE(wsB, 1, te & 1, 1), b, hid, h);
      if (te == NT - 1) h1fin = h;
    }
    gbar(cnt, gen);
  }

  // ============ transition ============
  out[(size_t)NB * NT * ND + (size_t)b * NH + hid] = h1fin;  // encoding
  c2 = c0; c3 = c1;
  store_h(AH_PLANE(wsB, 2, 1, 0), AH_PLANE(wsB, 2, 1, 1), b, hid, h0fin);
  store_h(AH_PLANE(wsB, 3, 1, 0), AH_PLANE(wsB, 3, 1, 1), b, hid, h1fin);

  float Gbreg[4];
  load_frags_single(dWih0, w, hb, lane, w0h, w0l);
  {  // Gb = db0 + encoding @ dWih0^T ; A = h1 plane par1 (published by last gbar)
    float4v acc[4] = {zacc, zacc, zacc, zacc};
    gemm_acc<4>(AH_PLANE(wsB, 1, 1, 0), AH_PLANE(wsB, 1, 1, 1), w * 4, aoff, w0h, w0l, acc);
    write_red(red, w, lane, acc);
    __syncthreads();
#pragma unroll
    for (int g = 0; g < 4; ++g) {
      float v = db0[g * NH + hid];
#pragma unroll
      for (int ww = 0; ww < 4; ++ww) v += red[((ww * 4 + g) * 16 + bi) * 16 + hi_];
      Gbreg[g] = v;
    }
  }
  load_frags_single(dWhh0, w, hb, lane, w0h, w0l);
  load_frags_concat(dWih1, dWhh1, w, hb, lane, w1h, w1l);
  gbar(cnt, gen);  // publishes h2/h3 par-1 init planes

  // ============ decoder: interval i does proj(t=i-2) || dec0(t=i) || dec1(t=i-1) ============
  for (int i = 0; i <= NT + 1; ++i) {
    if (i >= 2) {  // projection for tp=i-2, group-local: 16 b x 16 d = 256 dots
      const int tp = i - 2;
      const float* H3F = H3F_PTR(wsB, tp & 1);
      int idx = hb * 8 + w * 2;
#pragma unroll
      for (int rep = 0; rep < 2; ++rep, ++idx) {
        const int pb = b0 + (idx >> 4), pd = idx & 15;
        const float* hr = H3F + (size_t)pb * NH + lane * 8;
        const float* wr = Wout + (size_t)pd * NH + lane * 8;
        float ssum = 0.f;
#pragma unroll
        for (int j = 0; j < 8; ++j) ssum += hr[j] * wr[j];
#pragma unroll
        for (int off = 32; off >= 1; off >>= 1) ssum += __shfl_xor(ssum, off, 64);
        if (lane == 0) out[((size_t)pb * NT + tp) * ND + pd] = ssum + bout[pd];
      }
    }
    if (i < NT) {  // dec0(t=i): reads h2(i-1) @ par (i&1)^1
      const int pr = (i & 1) ^ 1;
      float4v acc[4] = {zacc, zacc, zacc, zacc};
      gemm_acc<4>(AH_PLANE(wsB, 2, pr, 0), AH_PLANE(wsB, 2, pr, 1), w * 4, aoff, w0h, w0l, acc);
      write_red(red, w, lane, acc);
      __syncthreads();
      float s[4];
#pragma unroll
      for (int g = 0; g < 4; ++g) {
        float v = Gbreg[g];
#pragma unroll
        for (int ww = 0; ww < 4; ++ww) v += red[((ww * 4 + g) * 16 + bi) * 16 + hi_];
        s[g] = v;
      }
      float ig = sigf(s[0]), fg = sigf(s[1]), gg = tanhf(s[2]), og = sigf(s[3]);
      c2 = fg * c2 + ig * gg;
      float h = og * tanhf(c2);
      store_h(AH_PLANE(wsB, 2, i & 1, 0), AH_PLANE(wsB, 2, i & 1, 1), b, hid, h);
    }
    __syncthreads();
    if (i >= 1 && i <= NT) {  // dec1(te=i-1): A=[h2(te) @ te&1 | h3(te-1) @ (te&1)^1]
      const int te = i - 1;
      const int pA = te & 1, pB = pA ^ 1;
      float4v acc[4] = {zacc, zacc, zacc, zacc};
      const int half = (w < 2);
      const char* pH = half ? AH_PLANE(wsB, 2, pA, 0) : AH_PLANE(wsB, 3, pB, 0);
      const char* pL = half ? AH_PLANE(wsB, 2, pA, 1) : AH_PLANE(wsB, 3, pB, 1);
      const int c0i = half ? w * 8 : (w - 2) * 8;
      gemm_acc<8>(pH, pL, c0i, aoff, w1h, w1l, acc);
      write_red(red, w, lane, acc);
      __syncthreads();
      float s[4];
#pragma unroll
      for (int g = 0; g < 4; ++g) {
        float v = db1v[g];
#pragma unroll
        for (int ww = 0; ww < 4; ++ww) v += red[((ww * 4 + g) * 16 + bi) * 16 + hi_];
        s[g] = v;
      }
      float ig = sigf(s[0]), fg = sigf(s[1]), gg = tanhf(s[2]), og = sigf(s[3]);
      c3 = fg * c3 + ig * gg;
      float h = og * tanhf(c3);
      store_h(AH_PLANE(wsB, 3, te & 1, 0), AH_PLANE(wsB, 3, te & 1, 1), b, hid, h);
      H3F_PTR(wsB, te & 1)[(size_t)b * NH + hid] = h;  // exact fp32 for projection
    }
    if (i != NT + 1) gbar(cnt, gen);
  }
}

extern "C" void kernel_launch(void* const* d_in, const int* in_sizes, int n_in,
                              void* d_out, int out_size, void* d_ws, size_t ws_size,
                              hipStream_t stream) {
  const float* xp    = (const float*)d_in[0];
  const float* eWih0 = (const float*)d_in[1];
  const float* eWhh0 = (const float*)d_in[2];
  const float* eb0   = (const float*)d_in[3];
  const float* eWih1 = (const float*)d_in[4];
  const float* eWhh1 = (const float*)d_in[5];
  const float* eb1   = (const float*)d_in[6];
  const float* dWih0 = (const float*)d_in[7];
  const float* dWhh0 = (const float*)d_in[8];
  const float* db0   = (const float*)d_in[9];
  const float* dWih1 = (const float*)d_in[10];
  const float* dWhh1 = (const float*)d_in[11];
  const float* db1   = (const float*)d_in[12];
  const float* Wout  = (const float*)d_in[13];
  const float* bout  = (const float*)d_in[14];

  hipMemsetAsync(d_ws, 0, BAR_BYTES, stream);  // all 8 group barriers
  lstm_ae_kernel<<<NWG, NTHR, 0, stream>>>(
      xp, eWih0, eWhh0, eb0, eWih1, eWhh1, eb1,
      dWih0, dWhh0, db0, dWih1, dWhh1, db1, Wout, bout,
      (float*)d_out, (char*)d_ws);
}

// Round 4
// 11240.557 us; speedup vs baseline: 21.1065x; 2.6211x over previous
//
#include <hip/hip_runtime.h>
#include <math.h>

// ---------------------------------------------------------------------------
// Round 4: fence-free coherence. All cross-WG state (h planes, H3F) moves
// through agent-scope RELAXED atomics (sc1 -> bypass L1/L2, coherent at the
// IF$/DF point). This removes every buffer_wbl2 / buffer_inv the round-3
// barrier implied (measured: fixed ~28us/interval regardless of arrival
// count + WRITE_SIZE == per-interval dirty set flushed to HBM).
//  - gbar: relaxed fetch_add arrival + relaxed epoch poll. Data visibility:
//    __syncthreads() drains each wave's vmcnt (m97-measured codegen); for
//    sc1 stores that ack == coherence-point visibility. Releaser orders
//    cnt-reset before gen-bump with one s_waitcnt(0).
//  - h planes packed 4B/elem (bf16 hi | lo<<16), chunk-tiled; A-frags
//    unpacked with ~8 VALU/chunk. Weights stay VGPR-resident (bf16x3 MFMA).
//  - Compute core unchanged from the passing round-2/3 kernel.
// ---------------------------------------------------------------------------

#define NB 128
#define NT 512
#define ND 16
#define NH 512
#define NWG 256
#define NTHR 256
#define NGRP 8
#define GWG 32

typedef __attribute__((ext_vector_type(8))) short short8;
typedef __attribute__((ext_vector_type(4))) float float4v;

#define SCOPE_AGT __HIP_MEMORY_SCOPE_AGENT

// ws layout:
//  [0, 8192)           8 group barriers, 1KB apart (cnt @+0, gen @+256)
//  [8192, +2MB)        8 h-planes (L in 0..3, parity) 256KB each, packed
//                      4B/elem: elem(b,k) at (k>>5)*16384 + b*128 + (k&31)*4
//  [+2MB, +2MB+512KB)  H3F fp32 planes [par][b][k] for the projection
#define BAR_BYTES 8192
#define PLANE_BYTES (NB * NH * 4)      // 262144
#define CHUNK_BYTES (32 * NB * 4)      // 16384
#define AH_PLANE(wsB, L, par) ((wsB) + BAR_BYTES + (size_t)((L) * 2 + (par)) * PLANE_BYTES)
#define H3F_PTR(wsB, par) ((float*)((wsB) + BAR_BYTES + 8 * (size_t)PLANE_BYTES + (size_t)(par) * NB * NH * 4))

// ---- agent-scope relaxed (sc1) accessors ----
__device__ __forceinline__ void st_u32(unsigned* p, unsigned v) {
  __hip_atomic_store(p, v, __ATOMIC_RELAXED, SCOPE_AGT);
}
__device__ __forceinline__ unsigned long long ld_u64(const void* p) {
  return __hip_atomic_load((const unsigned long long*)p, __ATOMIC_RELAXED, SCOPE_AGT);
}
__device__ __forceinline__ void st_f32(float* p, float v) {
  __hip_atomic_store(p, v, __ATOMIC_RELAXED, SCOPE_AGT);
}

// Fence-free group barrier. Correctness:
//  - __syncthreads() drains every wave's outstanding sc1 stores (vmcnt ack ==
//    coherence-point visibility for bypassing stores) before the leader
//    arrives, so all group data is globally visible before cnt is bumped.
//  - epoch is a monotone per-thread register: no gen pre-load race.
//  - releaser: cnt reset completes (s_waitcnt 0) before gen bump issues, so a
//    fast WG's next-barrier arrival can't be overwritten by the reset.
__device__ __forceinline__ void gbar(unsigned* cnt, unsigned* gen, unsigned& epoch) {
  ++epoch;
  __syncthreads();
  if (threadIdx.x == 0) {
    unsigned a = __hip_atomic_fetch_add(cnt, 1u, __ATOMIC_RELAXED, SCOPE_AGT);
    if (a == GWG - 1u) {
      __hip_atomic_store(cnt, 0u, __ATOMIC_RELAXED, SCOPE_AGT);
      __atomic_signal_fence(__ATOMIC_SEQ_CST);
      __builtin_amdgcn_s_waitcnt(0);
      __atomic_signal_fence(__ATOMIC_SEQ_CST);
      __hip_atomic_store(gen, epoch, __ATOMIC_RELAXED, SCOPE_AGT);
    } else {
      while ((int)(__hip_atomic_load(gen, __ATOMIC_RELAXED, SCOPE_AGT) - epoch) < 0)
        __builtin_amdgcn_s_sleep(1);
    }
  }
  __syncthreads();
}

__device__ __forceinline__ unsigned short f2bf(float f) {
  union { float f; unsigned u; } v; v.f = f;
  unsigned r = v.u + 0x7fffu + ((v.u >> 16) & 1u);  // RNE
  return (unsigned short)(r >> 16);
}
__device__ __forceinline__ float bf2f(unsigned short u) {
  union { float f; unsigned u; } v; v.u = ((unsigned)u) << 16; return v.f;
}
__device__ __forceinline__ void split2(float f, unsigned short& hi, unsigned short& lo) {
  hi = f2bf(f);
  lo = f2bf(f - bf2f(hi));
}

__device__ __forceinline__ void load_wfrag(const float* __restrict__ p, short8& h, short8& l) {
#pragma unroll
  for (int j = 0; j < 8; ++j) {
    unsigned short a, b2; split2(p[j], a, b2);
    h[j] = (short)a; l[j] = (short)b2;
  }
}

__device__ __forceinline__ void load_frags_single(const float* __restrict__ W, int w, int hb, int lane,
                                                  short8 (&fh)[4][4], short8 (&fl)[4][4]) {
  const int ln = lane & 15, lq = lane >> 4;
#pragma unroll
  for (int cc = 0; cc < 4; ++cc) {
    const int k = (w * 4 + cc) * 32 + lq * 8;
#pragma unroll
    for (int g = 0; g < 4; ++g) {
      const float* p = W + (size_t)(g * NH + hb * 16 + ln) * NH + k;
      load_wfrag(p, fh[cc][g], fl[cc][g]);
    }
  }
}

__device__ __forceinline__ void load_frags_concat(const float* __restrict__ Wa, const float* __restrict__ Wb,
                                                  int w, int hb, int lane,
                                                  short8 (&fh)[8][4], short8 (&fl)[8][4]) {
  const int ln = lane & 15, lq = lane >> 4;
#pragma unroll
  for (int cc = 0; cc < 8; ++cc) {
    const int k = (w * 8 + cc) * 32 + lq * 8;
    const float* W = (k < 512) ? Wa : Wb;
    const int kk = (k < 512) ? k : k - 512;
#pragma unroll
    for (int g = 0; g < 4; ++g) {
      const float* p = W + (size_t)(g * NH + hb * 16 + ln) * NH + kk;
      load_wfrag(p, fh[cc][g], fl[cc][g]);
    }
  }
}

// K-slice GEMM over a packed plane: NCH chunks starting at chunk c0.
template <int NCH>
__device__ __forceinline__ void gemm_acc(const char* __restrict__ plane, int c0, int aoff,
                                         const short8 (&wh)[NCH][4], const short8 (&wl)[NCH][4],
                                         float4v (&acc)[4]) {
#pragma unroll
  for (int cc = 0; cc < NCH; ++cc) {
    const char* base = plane + (size_t)(c0 + cc) * CHUNK_BYTES + aoff;
    unsigned long long q0 = ld_u64(base);
    unsigned long long q1 = ld_u64(base + 8);
    unsigned long long q2 = ld_u64(base + 16);
    unsigned long long q3 = ld_u64(base + 24);
    unsigned w0 = (unsigned)q0, w1 = (unsigned)(q0 >> 32);
    unsigned w2 = (unsigned)q1, w3 = (unsigned)(q1 >> 32);
    unsigned w4 = (unsigned)q2, w5 = (unsigned)(q2 >> 32);
    unsigned w6 = (unsigned)q3, w7 = (unsigned)(q3 >> 32);
    union U { unsigned u[4]; short8 s; } A, L;
    A.u[0] = (w0 & 0xffffu) | (w1 << 16);
    A.u[1] = (w2 & 0xffffu) | (w3 << 16);
    A.u[2] = (w4 & 0xffffu) | (w5 << 16);
    A.u[3] = (w6 & 0xffffu) | (w7 << 16);
    L.u[0] = (w0 >> 16) | (w1 & 0xffff0000u);
    L.u[1] = (w2 >> 16) | (w3 & 0xffff0000u);
    L.u[2] = (w4 >> 16) | (w5 & 0xffff0000u);
    L.u[3] = (w6 >> 16) | (w7 & 0xffff0000u);
    const short8 ah = A.s, al = L.s;
#pragma unroll
    for (int g = 0; g < 4; ++g) {
      acc[g] = __builtin_amdgcn_mfma_f32_16x16x32_bf16(ah, wh[cc][g], acc[g], 0, 0, 0);
      acc[g] = __builtin_amdgcn_mfma_f32_16x16x32_bf16(ah, wl[cc][g], acc[g], 0, 0, 0);
      acc[g] = __builtin_amdgcn_mfma_f32_16x16x32_bf16(al, wh[cc][g], acc[g], 0, 0, 0);
    }
  }
}

__device__ __forceinline__ void write_red(float* __restrict__ red, int w, int lane, const float4v (&acc)[4]) {
  const int ln = lane & 15, lq = lane >> 4;
#pragma unroll
  for (int g = 0; g < 4; ++g)
#pragma unroll
    for (int r = 0; r < 4; ++r)
      red[((w * 4 + g) * 16 + (lq * 4 + r)) * 16 + ln] = acc[g][r];
}

__device__ __forceinline__ void store_h(char* __restrict__ plane, int b, int hid, float h) {
  unsigned short hi, lo; split2(h, hi, lo);
  const size_t off = (size_t)(hid >> 5) * CHUNK_BYTES + (size_t)b * 128 + (size_t)(hid & 31) * 4;
  st_u32((unsigned*)(plane + off), (unsigned)hi | ((unsigned)lo << 16));
}

__device__ __forceinline__ float sigf(float v) { return 1.f / (1.f + __expf(-v)); }

extern "C" __global__ __launch_bounds__(NTHR, 1)
void lstm_ae_kernel(const float* __restrict__ x,
                    const float* __restrict__ eWih0, const float* __restrict__ eWhh0, const float* __restrict__ eb0,
                    const float* __restrict__ eWih1, const float* __restrict__ eWhh1, const float* __restrict__ eb1,
                    const float* __restrict__ dWih0, const float* __restrict__ dWhh0, const float* __restrict__ db0,
                    const float* __restrict__ dWih1, const float* __restrict__ dWhh1, const float* __restrict__ db1,
                    const float* __restrict__ Wout,  const float* __restrict__ bout,
                    float* __restrict__ out, char* __restrict__ wsB) {
  __shared__ float red[4 * 4 * 16 * 16];  // 16KB

  const int grp = blockIdx.x & 7;        // b-block == barrier group
  const int hb  = blockIdx.x >> 3;       // 0..31 hid-block
  unsigned* cnt = (unsigned*)(wsB + (size_t)grp * 1024);
  unsigned* gen = (unsigned*)(wsB + (size_t)grp * 1024 + 256);
  unsigned epoch = 0;

  const int tid  = threadIdx.x;
  const int lane = tid & 63;
  const int w    = tid >> 6;
  const int b0   = grp * 16;
  const int ln   = lane & 15, lq = lane >> 4;
  const int aoff = (b0 + ln) * 128 + lq * 32;   // byte offset within a chunk
  const int bi = tid >> 4, hi_ = tid & 15;
  const int b = b0 + bi, hid = hb * 16 + hi_;

  // ---- prologue ----
  store_h(AH_PLANE(wsB, 0, 1), b, hid, 0.f);
  store_h(AH_PLANE(wsB, 1, 1), b, hid, 0.f);
  float c0 = 0.f, c1 = 0.f, c2 = 0.f, c3 = 0.f;

  const float eb0v[4] = {eb0[hid], eb0[NH + hid], eb0[2 * NH + hid], eb0[3 * NH + hid]};
  const float eb1v[4] = {eb1[hid], eb1[NH + hid], eb1[2 * NH + hid], eb1[3 * NH + hid]};
  const float db1v[4] = {db1[hid], db1[NH + hid], db1[2 * NH + hid], db1[3 * NH + hid]};

  short8 w0h[4][4], w0l[4][4];
  short8 w1h[8][4], w1l[8][4];
  load_frags_single(eWhh0, w, hb, lane, w0h, w0l);
  load_frags_concat(eWih1, eWhh1, w, hb, lane, w1h, w1l);

  const float4v zacc = {0.f, 0.f, 0.f, 0.f};
  gbar(cnt, gen, epoch);

  float h0fin = 0.f, h1fin = 0.f;

  // ============ encoder: interval i does enc0(t=i) || enc1(t=i-1) ============
  for (int i = 0; i <= NT; ++i) {
    if (i < NT) {  // enc0(t=i): reads h0(i-1) @ par (i&1)^1, writes h0(i) @ par i&1
      const int pr = (i & 1) ^ 1;
      float4v acc[4] = {zacc, zacc, zacc, zacc};
      gemm_acc<4>(AH_PLANE(wsB, 0, pr), w * 4, aoff, w0h, w0l, acc);
      write_red(red, w, lane, acc);
      __syncthreads();
      float s[4];
#pragma unroll
      for (int g = 0; g < 4; ++g) {
        float v = eb0v[g];
#pragma unroll
        for (int ww = 0; ww < 4; ++ww) v += red[((ww * 4 + g) * 16 + bi) * 16 + hi_];
        s[g] = v;
      }
      const float* xr = x + ((size_t)b * NT + i) * ND;
      float xv[16];
#pragma unroll
      for (int j = 0; j < 16; ++j) xv[j] = xr[j];
#pragma unroll
      for (int g = 0; g < 4; ++g) {
        const float* wr = eWih0 + (size_t)(g * NH + hid) * ND;
        float v = 0.f;
#pragma unroll
        for (int j = 0; j < 16; ++j) v += xv[j] * wr[j];
        s[g] += v;
      }
      float ig = sigf(s[0]), fg = sigf(s[1]), gg = tanhf(s[2]), og = sigf(s[3]);
      c0 = fg * c0 + ig * gg;
      float h = og * tanhf(c0);
      store_h(AH_PLANE(wsB, 0, i & 1), b, hid, h);
      if (i == NT - 1) h0fin = h;
    }
    __syncthreads();  // red reuse fence
    if (i >= 1) {  // enc1(te=i-1): A=[h0(te) @ par te&1 | h1(te-1) @ par (te&1)^1]
      const int te = i - 1;
      const int pA = te & 1, pB = pA ^ 1;
      float4v acc[4] = {zacc, zacc, zacc, zacc};
      const int half = (w < 2);
      const char* pl = half ? AH_PLANE(wsB, 0, pA) : AH_PLANE(wsB, 1, pB);
      const int c0i = half ? w * 8 : (w - 2) * 8;
      gemm_acc<8>(pl, c0i, aoff, w1h, w1l, acc);
      write_red(red, w, lane, acc);
      __syncthreads();
      float s[4];
#pragma unroll
      for (int g = 0; g < 4; ++g) {
        float v = eb1v[g];
#pragma unroll
        for (int ww = 0; ww < 4; ++ww) v += red[((ww * 4 + g) * 16 + bi) * 16 + hi_];
        s[g] = v;
      }
      float ig = sigf(s[0]), fg = sigf(s[1]), gg = tanhf(s[2]), og = sigf(s[3]);
      c1 = fg * c1 + ig * gg;
      float h = og * tanhf(c1);
      store_h(AH_PLANE(wsB, 1, te & 1), b, hid, h);
      if (te == NT - 1) h1fin = h;
    }
    gbar(cnt, gen, epoch);
  }

  // ============ transition ============
  out[(size_t)NB * NT * ND + (size_t)b * NH + hid] = h1fin;  // encoding
  c2 = c0; c3 = c1;
  store_h(AH_PLANE(wsB, 2, 1), b, hid, h0fin);
  store_h(AH_PLANE(wsB, 3, 1), b, hid, h1fin);

  float Gbreg[4];
  load_frags_single(dWih0, w, hb, lane, w0h, w0l);
  {  // Gb = db0 + encoding @ dWih0^T ; A = h1 plane par1 (published by last gbar)
    float4v acc[4] = {zacc, zacc, zacc, zacc};
    gemm_acc<4>(AH_PLANE(wsB, 1, 1), w * 4, aoff, w0h, w0l, acc);
    write_red(red, w, lane, acc);
    __syncthreads();
#pragma unroll
    for (int g = 0; g < 4; ++g) {
      float v = db0[g * NH + hid];
#pragma unroll
      for (int ww = 0; ww < 4; ++ww) v += red[((ww * 4 + g) * 16 + bi) * 16 + hi_];
      Gbreg[g] = v;
    }
  }
  load_frags_single(dWhh0, w, hb, lane, w0h, w0l);
  load_frags_concat(dWih1, dWhh1, w, hb, lane, w1h, w1l);
  gbar(cnt, gen, epoch);  // publishes h2/h3 par-1 init planes

  // ============ decoder: interval i does proj(t=i-2) || dec0(t=i) || dec1(t=i-1) ============
  for (int i = 0; i <= NT + 1; ++i) {
    if (i >= 2) {  // projection for tp=i-2, group-local: 16 b x 16 d
      const int tp = i - 2;
      const float* H3F = H3F_PTR(wsB, tp & 1);
      int idx = hb * 8 + w * 2;
#pragma unroll
      for (int rep = 0; rep < 2; ++rep, ++idx) {
        const int pb = b0 + (idx >> 4), pd = idx & 15;
        const char* hq = (const char*)(H3F + (size_t)pb * NH + lane * 8);
        unsigned long long a0 = ld_u64(hq), a1 = ld_u64(hq + 8),
                           a2 = ld_u64(hq + 16), a3 = ld_u64(hq + 24);
        union Q { unsigned long long q; float f[2]; } u0, u1, u2, u3;
        u0.q = a0; u1.q = a1; u2.q = a2; u3.q = a3;
        const float* wr = Wout + (size_t)pd * NH + lane * 8;
        float ssum = u0.f[0] * wr[0] + u0.f[1] * wr[1] + u1.f[0] * wr[2] + u1.f[1] * wr[3]
                   + u2.f[0] * wr[4] + u2.f[1] * wr[5] + u3.f[0] * wr[6] + u3.f[1] * wr[7];
#pragma unroll
        for (int off = 32; off >= 1; off >>= 1) ssum += __shfl_xor(ssum, off, 64);
        if (lane == 0) out[((size_t)pb * NT + tp) * ND + pd] = ssum + bout[pd];
      }
    }
    if (i < NT) {  // dec0(t=i): reads h2(i-1) @ par (i&1)^1
      const int pr = (i & 1) ^ 1;
      float4v acc[4] = {zacc, zacc, zacc, zacc};
      gemm_acc<4>(AH_PLANE(wsB, 2, pr), w * 4, aoff, w0h, w0l, acc);
      write_red(red, w, lane, acc);
      __syncthreads();
      float s[4];
#pragma unroll
      for (int g = 0; g < 4; ++g) {
        float v = Gbreg[g];
#pragma unroll
        for (int ww = 0; ww < 4; ++ww) v += red[((ww * 4 + g) * 16 + bi) * 16 + hi_];
        s[g] = v;
      }
      float ig = sigf(s[0]), fg = sigf(s[1]), gg = tanhf(s[2]), og = sigf(s[3]);
      c2 = fg * c2 + ig * gg;
      float h = og * tanhf(c2);
      store_h(AH_PLANE(wsB, 2, i & 1), b, hid, h);
    }
    __syncthreads();
    if (i >= 1 && i <= NT) {  // dec1(te=i-1): A=[h2(te) @ te&1 | h3(te-1) @ (te&1)^1]
      const int te = i - 1;
      const int pA = te & 1, pB = pA ^ 1;
      float4v acc[4] = {zacc, zacc, zacc, zacc};
      const int half = (w < 2);
      const char* pl = half ? AH_PLANE(wsB, 2, pA) : AH_PLANE(wsB, 3, pB);
      const int c0i = half ? w * 8 : (w - 2) * 8;
      gemm_acc<8>(pl, c0i, aoff, w1h, w1l, acc);
      write_red(red, w, lane, acc);
      __syncthreads();
      float s[4];
#pragma unroll
      for (int g = 0; g < 4; ++g) {
        float v = db1v[g];
#pragma unroll
        for (int ww = 0; ww < 4; ++ww) v += red[((ww * 4 + g) * 16 + bi) * 16 + hi_];
        s[g] = v;
      }
      float ig = sigf(s[0]), fg = sigf(s[1]), gg = tanhf(s[2]), og = sigf(s[3]);
      c3 = fg * c3 + ig * gg;
      float h = og * tanhf(c3);
      store_h(AH_PLANE(wsB, 3, te & 1), b, hid, h);
      st_f32(H3F_PTR(wsB, te & 1) + (size_t)b * NH + hid, h);  // fp32 for projection
    }
    if (i != NT + 1) gbar(cnt, gen, epoch);
  }
}

extern "C" void kernel_launch(void* const* d_in, const int* in_sizes, int n_in,
                              void* d_out, int out_size, void* d_ws, size_t ws_size,
                              hipStream_t stream) {
  const float* xp    = (const float*)d_in[0];
  const float* eWih0 = (const float*)d_in[1];
  const float* eWhh0 = (const float*)d_in[2];
  const float* eb0   = (const float*)d_in[3];
  const float* eWih1 = (const float*)d_in[4];
  const float* eWhh1 = (const float*)d_in[5];
  const float* eb1   = (const float*)d_in[6];
  const float* dWih0 = (const float*)d_in[7];
  const float* dWhh0 = (const float*)d_in[8];
  const float* db0   = (const float*)d_in[9];
  const float* dWih1 = (const float*)d_in[10];
  const float* dWhh1 = (const float*)d_in[11];
  const float* db1   = (const float*)d_in[12];
  const float* Wout  = (const float*)d_in[13];
  const float* bout  = (const float*)d_in[14];

  hipMemsetAsync(d_ws, 0, BAR_BYTES, stream);  // group barrier words
  lstm_ae_kernel<<<NWG, NTHR, 0, stream>>>(
      xp, eWih0, eWhh0, eb0, eWih1, eWhh1, eb1,
      dWih0, dWhh0, db0, dWih1, dWhh1, db1, Wout, bout,
      (float*)d_out, (char*)d_ws);
}

// Round 5
// 11089.789 us; speedup vs baseline: 21.3935x; 1.0136x over previous
//
#include <hip/hip_runtime.h>
#include <math.h>

// ---------------------------------------------------------------------------
// Round 5: all-poll flag-array barrier (no RMW chain, no release hop).
//  - Round-4 measured: ~9 of 10.9 us/interval was the counter barrier
//    (32 serialized same-line fetch_adds at the coherence point + releaser
//    waitcnt + gen propagation + poll detection).
//  - New barrier: WG-leader stores monotone epoch to its own 4B slot
//    (32 parallel stores). One wave polls all 32 flags with ONE coalesced
//    sc1 load per round (lane l reads flag l) + __all ballot. No resets,
//    no releaser, no fences. Expected ~0.7-1 us.
//  - Data path unchanged from round 4: h planes via agent-scope relaxed
//    (sc1) atomics, packed 4B/elem; weights VGPR-resident bf16x3 MFMA;
//    enc0(t)||enc1(t-1) and proj(t-2)||dec0(t)||dec1(t-1) pipelining.
// ---------------------------------------------------------------------------

#define NB 128
#define NT 512
#define ND 16
#define NH 512
#define NWG 256
#define NTHR 256
#define NGRP 8
#define GWG 32

typedef __attribute__((ext_vector_type(8))) short short8;
typedef __attribute__((ext_vector_type(4))) float float4v;

#define SCOPE_AGT __HIP_MEMORY_SCOPE_AGENT

// ws layout:
//  [0, 8192)           8 groups x 1KB: flags[32] (4B each) at +0
//  [8192, +2MB)        8 h-planes (L in 0..3, parity) 256KB each, packed
//                      4B/elem: elem(b,k) at (k>>5)*16384 + b*128 + (k&31)*4
//  [+2MB, +2MB+512KB)  H3F fp32 planes [par][b][k] for the projection
#define BAR_BYTES 8192
#define PLANE_BYTES (NB * NH * 4)      // 262144
#define CHUNK_BYTES (32 * NB * 4)      // 16384
#define AH_PLANE(wsB, L, par) ((wsB) + BAR_BYTES + (size_t)((L) * 2 + (par)) * PLANE_BYTES)
#define H3F_PTR(wsB, par) ((float*)((wsB) + BAR_BYTES + 8 * (size_t)PLANE_BYTES + (size_t)(par) * NB * NH * 4))

// ---- agent-scope relaxed (sc1) accessors ----
__device__ __forceinline__ void st_u32(unsigned* p, unsigned v) {
  __hip_atomic_store(p, v, __ATOMIC_RELAXED, SCOPE_AGT);
}
__device__ __forceinline__ unsigned long long ld_u64(const void* p) {
  return __hip_atomic_load((const unsigned long long*)p, __ATOMIC_RELAXED, SCOPE_AGT);
}
__device__ __forceinline__ void st_f32(float* p, float v) {
  __hip_atomic_store(p, v, __ATOMIC_RELAXED, SCOPE_AGT);
}

// All-poll flag barrier. Correctness:
//  - __syncthreads() drains every wave's outstanding sc1 stores (vmcnt ack ==
//    coherence-point visibility) before the leader publishes its epoch, so
//    all group data is visible before any flag says "arrived".
//  - epoch is monotone, flags are never reset -> no reset/arrival race; '>='
//    comparison tolerates any skew. Lane-parallel poll: one coalesced 4B x32
//    load per round.
__device__ __forceinline__ void gbar(unsigned* flags, int hb, unsigned& epoch) {
  ++epoch;
  __syncthreads();
  if (threadIdx.x < 64) {
    if (threadIdx.x == 0)
      __hip_atomic_store(flags + hb, epoch, __ATOMIC_RELAXED, SCOPE_AGT);
    const int l = threadIdx.x;
    for (;;) {
      unsigned v = (l < GWG) ? __hip_atomic_load(flags + l, __ATOMIC_RELAXED, SCOPE_AGT) : epoch;
      if (__all((int)(v - epoch) >= 0)) break;
      __builtin_amdgcn_s_sleep(1);
    }
  }
  __syncthreads();
}

__device__ __forceinline__ unsigned short f2bf(float f) {
  union { float f; unsigned u; } v; v.f = f;
  unsigned r = v.u + 0x7fffu + ((v.u >> 16) & 1u);  // RNE
  return (unsigned short)(r >> 16);
}
__device__ __forceinline__ float bf2f(unsigned short u) {
  union { float f; unsigned u; } v; v.u = ((unsigned)u) << 16; return v.f;
}
__device__ __forceinline__ void split2(float f, unsigned short& hi, unsigned short& lo) {
  hi = f2bf(f);
  lo = f2bf(f - bf2f(hi));
}

__device__ __forceinline__ void load_wfrag(const float* __restrict__ p, short8& h, short8& l) {
#pragma unroll
  for (int j = 0; j < 8; ++j) {
    unsigned short a, b2; split2(p[j], a, b2);
    h[j] = (short)a; l[j] = (short)b2;
  }
}

__device__ __forceinline__ void load_frags_single(const float* __restrict__ W, int w, int hb, int lane,
                                                  short8 (&fh)[4][4], short8 (&fl)[4][4]) {
  const int ln = lane & 15, lq = lane >> 4;
#pragma unroll
  for (int cc = 0; cc < 4; ++cc) {
    const int k = (w * 4 + cc) * 32 + lq * 8;
#pragma unroll
    for (int g = 0; g < 4; ++g) {
      const float* p = W + (size_t)(g * NH + hb * 16 + ln) * NH + k;
      load_wfrag(p, fh[cc][g], fl[cc][g]);
    }
  }
}

__device__ __forceinline__ void load_frags_concat(const float* __restrict__ Wa, const float* __restrict__ Wb,
                                                  int w, int hb, int lane,
                                                  short8 (&fh)[8][4], short8 (&fl)[8][4]) {
  const int ln = lane & 15, lq = lane >> 4;
#pragma unroll
  for (int cc = 0; cc < 8; ++cc) {
    const int k = (w * 8 + cc) * 32 + lq * 8;
    const float* W = (k < 512) ? Wa : Wb;
    const int kk = (k < 512) ? k : k - 512;
#pragma unroll
    for (int g = 0; g < 4; ++g) {
      const float* p = W + (size_t)(g * NH + hb * 16 + ln) * NH + kk;
      load_wfrag(p, fh[cc][g], fl[cc][g]);
    }
  }
}

// K-slice GEMM over a packed plane: NCH chunks starting at chunk c0.
template <int NCH>
__device__ __forceinline__ void gemm_acc(const char* __restrict__ plane, int c0, int aoff,
                                         const short8 (&wh)[NCH][4], const short8 (&wl)[NCH][4],
                                         float4v (&acc)[4]) {
#pragma unroll
  for (int cc = 0; cc < NCH; ++cc) {
    const char* base = plane + (size_t)(c0 + cc) * CHUNK_BYTES + aoff;
    unsigned long long q0 = ld_u64(base);
    unsigned long long q1 = ld_u64(base + 8);
    unsigned long long q2 = ld_u64(base + 16);
    unsigned long long q3 = ld_u64(base + 24);
    unsigned w0 = (unsigned)q0, w1 = (unsigned)(q0 >> 32);
    unsigned w2 = (unsigned)q1, w3 = (unsigned)(q1 >> 32);
    unsigned w4 = (unsigned)q2, w5 = (unsigned)(q2 >> 32);
    unsigned w6 = (unsigned)q3, w7 = (unsigned)(q3 >> 32);
    union U { unsigned u[4]; short8 s; } A, L;
    A.u[0] = (w0 & 0xffffu) | (w1 << 16);
    A.u[1] = (w2 & 0xffffu) | (w3 << 16);
    A.u[2] = (w4 & 0xffffu) | (w5 << 16);
    A.u[3] = (w6 & 0xffffu) | (w7 << 16);
    L.u[0] = (w0 >> 16) | (w1 & 0xffff0000u);
    L.u[1] = (w2 >> 16) | (w3 & 0xffff0000u);
    L.u[2] = (w4 >> 16) | (w5 & 0xffff0000u);
    L.u[3] = (w6 >> 16) | (w7 & 0xffff0000u);
    const short8 ah = A.s, al = L.s;
#pragma unroll
    for (int g = 0; g < 4; ++g) {
      acc[g] = __builtin_amdgcn_mfma_f32_16x16x32_bf16(ah, wh[cc][g], acc[g], 0, 0, 0);
      acc[g] = __builtin_amdgcn_mfma_f32_16x16x32_bf16(ah, wl[cc][g], acc[g], 0, 0, 0);
      acc[g] = __builtin_amdgcn_mfma_f32_16x16x32_bf16(al, wh[cc][g], acc[g], 0, 0, 0);
    }
  }
}

__device__ __forceinline__ void write_red(float* __restrict__ red, int w, int lane, const float4v (&acc)[4]) {
  const int ln = lane & 15, lq = lane >> 4;
#pragma unroll
  for (int g = 0; g < 4; ++g)
#pragma unroll
    for (int r = 0; r < 4; ++r)
      red[((w * 4 + g) * 16 + (lq * 4 + r)) * 16 + ln] = acc[g][r];
}

__device__ __forceinline__ void store_h(char* __restrict__ plane, int b, int hid, float h) {
  unsigned short hi, lo; split2(h, hi, lo);
  const size_t off = (size_t)(hid >> 5) * CHUNK_BYTES + (size_t)b * 128 + (size_t)(hid & 31) * 4;
  st_u32((unsigned*)(plane + off), (unsigned)hi | ((unsigned)lo << 16));
}

__device__ __forceinline__ float sigf(float v) { return 1.f / (1.f + __expf(-v)); }

extern "C" __global__ __launch_bounds__(NTHR, 1)
void lstm_ae_kernel(const float* __restrict__ x,
                    const float* __restrict__ eWih0, const float* __restrict__ eWhh0, const float* __restrict__ eb0,
                    const float* __restrict__ eWih1, const float* __restrict__ eWhh1, const float* __restrict__ eb1,
                    const float* __restrict__ dWih0, const float* __restrict__ dWhh0, const float* __restrict__ db0,
                    const float* __restrict__ dWih1, const float* __restrict__ dWhh1, const float* __restrict__ db1,
                    const float* __restrict__ Wout,  const float* __restrict__ bout,
                    float* __restrict__ out, char* __restrict__ wsB) {
  __shared__ float red[4 * 4 * 16 * 16];  // 16KB

  const int grp = blockIdx.x & 7;        // b-block == barrier group
  const int hb  = blockIdx.x >> 3;       // 0..31 hid-block
  unsigned* flags = (unsigned*)(wsB + (size_t)grp * 1024);
  unsigned epoch = 0;

  const int tid  = threadIdx.x;
  const int lane = tid & 63;
  const int w    = tid >> 6;
  const int b0   = grp * 16;
  const int ln   = lane & 15, lq = lane >> 4;
  const int aoff = (b0 + ln) * 128 + lq * 32;   // byte offset within a chunk
  const int bi = tid >> 4, hi_ = tid & 15;
  const int b = b0 + bi, hid = hb * 16 + hi_;

  // ---- prologue ----
  store_h(AH_PLANE(wsB, 0, 1), b, hid, 0.f);
  store_h(AH_PLANE(wsB, 1, 1), b, hid, 0.f);
  float c0 = 0.f, c1 = 0.f, c2 = 0.f, c3 = 0.f;

  const float eb0v[4] = {eb0[hid], eb0[NH + hid], eb0[2 * NH + hid], eb0[3 * NH + hid]};
  const float eb1v[4] = {eb1[hid], eb1[NH + hid], eb1[2 * NH + hid], eb1[3 * NH + hid]};
  const float db1v[4] = {db1[hid], db1[NH + hid], db1[2 * NH + hid], db1[3 * NH + hid]};

  short8 w0h[4][4], w0l[4][4];
  short8 w1h[8][4], w1l[8][4];
  load_frags_single(eWhh0, w, hb, lane, w0h, w0l);
  load_frags_concat(eWih1, eWhh1, w, hb, lane, w1h, w1l);

  const float4v zacc = {0.f, 0.f, 0.f, 0.f};
  gbar(flags, hb, epoch);

  float h0fin = 0.f, h1fin = 0.f;

  // ============ encoder: interval i does enc0(t=i) || enc1(t=i-1) ============
  for (int i = 0; i <= NT; ++i) {
    if (i < NT) {  // enc0(t=i): reads h0(i-1) @ par (i&1)^1, writes h0(i) @ par i&1
      const int pr = (i & 1) ^ 1;
      float4v acc[4] = {zacc, zacc, zacc, zacc};
      gemm_acc<4>(AH_PLANE(wsB, 0, pr), w * 4, aoff, w0h, w0l, acc);
      write_red(red, w, lane, acc);
      __syncthreads();
      float s[4];
#pragma unroll
      for (int g = 0; g < 4; ++g) {
        float v = eb0v[g];
#pragma unroll
        for (int ww = 0; ww < 4; ++ww) v += red[((ww * 4 + g) * 16 + bi) * 16 + hi_];
        s[g] = v;
      }
      const float* xr = x + ((size_t)b * NT + i) * ND;
      float xv[16];
#pragma unroll
      for (int j = 0; j < 16; ++j) xv[j] = xr[j];
#pragma unroll
      for (int g = 0; g < 4; ++g) {
        const float* wr = eWih0 + (size_t)(g * NH + hid) * ND;
        float v = 0.f;
#pragma unroll
        for (int j = 0; j < 16; ++j) v += xv[j] * wr[j];
        s[g] += v;
      }
      float ig = sigf(s[0]), fg = sigf(s[1]), gg = tanhf(s[2]), og = sigf(s[3]);
      c0 = fg * c0 + ig * gg;
      float h = og * tanhf(c0);
      store_h(AH_PLANE(wsB, 0, i & 1), b, hid, h);
      if (i == NT - 1) h0fin = h;
    }
    __syncthreads();  // red reuse fence
    if (i >= 1) {  // enc1(te=i-1): A=[h0(te) @ par te&1 | h1(te-1) @ par (te&1)^1]
      const int te = i - 1;
      const int pA = te & 1, pB = pA ^ 1;
      float4v acc[4] = {zacc, zacc, zacc, zacc};
      const int half = (w < 2);
      const char* pl = half ? AH_PLANE(wsB, 0, pA) : AH_PLANE(wsB, 1, pB);
      const int c0i = half ? w * 8 : (w - 2) * 8;
      gemm_acc<8>(pl, c0i, aoff, w1h, w1l, acc);
      write_red(red, w, lane, acc);
      __syncthreads();
      float s[4];
#pragma unroll
      for (int g = 0; g < 4; ++g) {
        float v = eb1v[g];
#pragma unroll
        for (int ww = 0; ww < 4; ++ww) v += red[((ww * 4 + g) * 16 + bi) * 16 + hi_];
        s[g] = v;
      }
      float ig = sigf(s[0]), fg = sigf(s[1]), gg = tanhf(s[2]), og = sigf(s[3]);
      c1 = fg * c1 + ig * gg;
      float h = og * tanhf(c1);
      store_h(AH_PLANE(wsB, 1, te & 1), b, hid, h);
      if (te == NT - 1) h1fin = h;
    }
    gbar(flags, hb, epoch);
  }

  // ============ transition ============
  out[(size_t)NB * NT * ND + (size_t)b * NH + hid] = h1fin;  // encoding
  c2 = c0; c3 = c1;
  store_h(AH_PLANE(wsB, 2, 1), b, hid, h0fin);
  store_h(AH_PLANE(wsB, 3, 1), b, hid, h1fin);

  float Gbreg[4];
  load_frags_single(dWih0, w, hb, lane, w0h, w0l);
  {  // Gb = db0 + encoding @ dWih0^T ; A = h1 plane par1 (published by last gbar)
    float4v acc[4] = {zacc, zacc, zacc, zacc};
    gemm_acc<4>(AH_PLANE(wsB, 1, 1), w * 4, aoff, w0h, w0l, acc);
    write_red(red, w, lane, acc);
    __syncthreads();
#pragma unroll
    for (int g = 0; g < 4; ++g) {
      float v = db0[g * NH + hid];
#pragma unroll
      for (int ww = 0; ww < 4; ++ww) v += red[((ww * 4 + g) * 16 + bi) * 16 + hi_];
      Gbreg[g] = v;
    }
  }
  load_frags_single(dWhh0, w, hb, lane, w0h, w0l);
  load_frags_concat(dWih1, dWhh1, w, hb, lane, w1h, w1l);
  gbar(flags, hb, epoch);  // publishes h2/h3 par-1 init planes

  // ============ decoder: interval i does proj(t=i-2) || dec0(t=i) || dec1(t=i-1) ============
  for (int i = 0; i <= NT + 1; ++i) {
    if (i >= 2) {  // projection for tp=i-2, group-local: 16 b x 16 d
      const int tp = i - 2;
      const float* H3F = H3F_PTR(wsB, tp & 1);
      int idx = hb * 8 + w * 2;
#pragma unroll
      for (int rep = 0; rep < 2; ++rep, ++idx) {
        const int pb = b0 + (idx >> 4), pd = idx & 15;
        const char* hq = (const char*)(H3F + (size_t)pb * NH + lane * 8);
        unsigned long long a0 = ld_u64(hq), a1 = ld_u64(hq + 8),
                           a2 = ld_u64(hq + 16), a3 = ld_u64(hq + 24);
        union Q { unsigned long long q; float f[2]; } u0, u1, u2, u3;
        u0.q = a0; u1.q = a1; u2.q = a2; u3.q = a3;
        const float* wr = Wout + (size_t)pd * NH + lane * 8;
        float ssum = u0.f[0] * wr[0] + u0.f[1] * wr[1] + u1.f[0] * wr[2] + u1.f[1] * wr[3]
                   + u2.f[0] * wr[4] + u2.f[1] * wr[5] + u3.f[0] * wr[6] + u3.f[1] * wr[7];
#pragma unroll
        for (int off = 32; off >= 1; off >>= 1) ssum += __shfl_xor(ssum, off, 64);
        if (lane == 0) out[((size_t)pb * NT + tp) * ND + pd] = ssum + bout[pd];
      }
    }
    if (i < NT) {  // dec0(t=i): reads h2(i-1) @ par (i&1)^1
      const int pr = (i & 1) ^ 1;
      float4v acc[4] = {zacc, zacc, zacc, zacc};
      gemm_acc<4>(AH_PLANE(wsB, 2, pr), w * 4, aoff, w0h, w0l, acc);
      write_red(red, w, lane, acc);
      __syncthreads();
      float s[4];
#pragma unroll
      for (int g = 0; g < 4; ++g) {
        float v = Gbreg[g];
#pragma unroll
        for (int ww = 0; ww < 4; ++ww) v += red[((ww * 4 + g) * 16 + bi) * 16 + hi_];
        s[g] = v;
      }
      float ig = sigf(s[0]), fg = sigf(s[1]), gg = tanhf(s[2]), og = sigf(s[3]);
      c2 = fg * c2 + ig * gg;
      float h = og * tanhf(c2);
      store_h(AH_PLANE(wsB, 2, i & 1), b, hid, h);
    }
    __syncthreads();
    if (i >= 1 && i <= NT) {  // dec1(te=i-1): A=[h2(te) @ te&1 | h3(te-1) @ (te&1)^1]
      const int te = i - 1;
      const int pA = te & 1, pB = pA ^ 1;
      float4v acc[4] = {zacc, zacc, zacc, zacc};
      const int half = (w < 2);
      const char* pl = half ? AH_PLANE(wsB, 2, pA) : AH_PLANE(wsB, 3, pB);
      const int c0i = half ? w * 8 : (w - 2) * 8;
      gemm_acc<8>(pl, c0i, aoff, w1h, w1l, acc);
      write_red(red, w, lane, acc);
      __syncthreads();
      float s[4];
#pragma unroll
      for (int g = 0; g < 4; ++g) {
        float v = db1v[g];
#pragma unroll
        for (int ww = 0; ww < 4; ++ww) v += red[((ww * 4 + g) * 16 + bi) * 16 + hi_];
        s[g] = v;
      }
      float ig = sigf(s[0]), fg = sigf(s[1]), gg = tanhf(s[2]), og = sigf(s[3]);
      c3 = fg * c3 + ig * gg;
      float h = og * tanhf(c3);
      store_h(AH_PLANE(wsB, 3, te & 1), b, hid, h);
      st_f32(H3F_PTR(wsB, te & 1) + (size_t)b * NH + hid, h);  // fp32 for projection
    }
    if (i != NT + 1) gbar(flags, hb, epoch);
  }
}

extern "C" void kernel_launch(void* const* d_in, const int* in_sizes, int n_in,
                              void* d_out, int out_size, void* d_ws, size_t ws_size,
                              hipStream_t stream) {
  const float* xp    = (const float*)d_in[0];
  const float* eWih0 = (const float*)d_in[1];
  const float* eWhh0 = (const float*)d_in[2];
  const float* eb0   = (const float*)d_in[3];
  const float* eWih1 = (const float*)d_in[4];
  const float* eWhh1 = (const float*)d_in[5];
  const float* eb1   = (const float*)d_in[6];
  const float* dWih0 = (const float*)d_in[7];
  const float* dWhh0 = (const float*)d_in[8];
  const float* db0   = (const float*)d_in[9];
  const float* dWih1 = (const float*)d_in[10];
  const float* dWhh1 = (const float*)d_in[11];
  const float* db1   = (const float*)d_in[12];
  const float* Wout  = (const float*)d_in[13];
  const float* bout  = (const float*)d_in[14];

  hipMemsetAsync(d_ws, 0, BAR_BYTES, stream);  // zero all group flags
  lstm_ae_kernel<<<NWG, NTHR, 0, stream>>>(
      xp, eWih0, eWhh0, eb0, eWih1, eWhh1, eb1,
      dWih0, dWhh0, db0, dWih1, dWhh1, db1, Wout, bout,
      (float*)d_out, (char*)d_ws);
}

// Round 8
// 8714.984 us; speedup vs baseline: 27.2231x; 1.2725x over previous
//
#include <hip/hip_runtime.h>
#include <math.h>

// ---------------------------------------------------------------------------
// Round 8: XCD-local data path by CONSTRUCTION (roster), single-instantiation
// body, minimal inline asm.
//  - R6/R7 crash suspects eliminated: (a) body instantiated ONCE with a
//    runtime `fast` flag (R6/R7 doubled the giant body); (b) asm blocks are
//    small (2 chunks = 16 early-clobber VGPRs, s_waitcnt inside the block);
//    (c) no placement *check* to get wrong: group = physical XCD via roster
//    (slot = fetch_add(cnt[XCC_ID])), so co-location is true by definition;
//    one-time device-wide verification (all counts == 32) else global
//    fallback to the R5-proven blockIdx mapping + sc1 data path.
//  - Barrier: EXACT R5 sc1 flag barrier (proven). Only data moves to
//    plain stores + sc0 loads (XCD-L2 coherent within a roster group).
//  - Core unchanged: VGPR-resident bf16x3 weights, 16x16x32 MFMA, split-K
//    LDS reduction (now red0/red1, one mid sync), enc0(t)||enc1(t-1),
//    proj(t-2)||dec0(t)||dec1(t-1) pipelining.
// ---------------------------------------------------------------------------

#define NB 128
#define NT 512
#define ND 16
#define NH 512
#define NWG 256
#define NTHR 256
#define NGRP 8
#define GWG 32

typedef __attribute__((ext_vector_type(8))) short short8;
typedef __attribute__((ext_vector_type(4))) float float4v;
typedef __attribute__((ext_vector_type(4))) unsigned int uint4v;

#define SCOPE_AGT __HIP_MEMORY_SCOPE_AGENT
#define SCOPE_WG  __HIP_MEMORY_SCOPE_WORKGROUP

// ws layout (first 16KB zeroed every launch):
//  [0, 8192)        8 groups x 1KB: flags[32] (sc1 barrier words)
//  [9216, 9248)     xcnt[8] roster counters
//  [10240, 11264)   gflags[256] one-time global barrier
//  [16384, +2MB)    8 h-planes (L 0..3, parity) 256KB each, packed 4B/elem:
//                   elem(b,k) at (k>>5)*16384 + b*128 + (k&31)*4
//  [+2MB, +512KB)   H3F fp32 planes [par][b][k]
#define BAR_BYTES 16384
#define PLANE_BYTES (NB * NH * 4)
#define CHUNK_BYTES (32 * NB * 4)
#define AH_PLANE(wsB, L, par) ((wsB) + BAR_BYTES + (size_t)((L) * 2 + (par)) * PLANE_BYTES)
#define H3F_PTR(wsB, par) ((float*)((wsB) + BAR_BYTES + 8 * (size_t)PLANE_BYTES + (size_t)(par) * NB * NH * 4))

// ---- sc1 (device coherence point) accessors ----
__device__ __forceinline__ void st_u32_agt(unsigned* p, unsigned v) {
  __hip_atomic_store(p, v, __ATOMIC_RELAXED, SCOPE_AGT);
}
__device__ __forceinline__ unsigned ld_u32_agt(const unsigned* p) {
  return __hip_atomic_load(p, __ATOMIC_RELAXED, SCOPE_AGT);
}
__device__ __forceinline__ unsigned long long ld_u64_agt(const void* p) {
  return __hip_atomic_load((const unsigned long long*)p, __ATOMIC_RELAXED, SCOPE_AGT);
}

// 2-chunk load (32B/lane each). fast: one small self-contained asm block
// (sc0 = L1-bypass, XCD-L2 coherent; wait inside; 16 early-clobber VGPRs).
// slow: sc1 atomic loads (R5-proven).
__device__ __forceinline__ void loadpair(bool fast, const char* pa, const char* pb,
                                         uint4v (&d)[4]) {
  if (fast) {
    asm volatile(
        "global_load_dwordx4 %0, %4, off sc0\n\t"
        "global_load_dwordx4 %1, %4, off offset:16 sc0\n\t"
        "global_load_dwordx4 %2, %5, off sc0\n\t"
        "global_load_dwordx4 %3, %5, off offset:16 sc0\n\t"
        "s_waitcnt vmcnt(0)"
        : "=&v"(d[0]), "=&v"(d[1]), "=&v"(d[2]), "=&v"(d[3])
        : "v"(pa), "v"(pb)
        : "memory");
  } else {
#pragma unroll
    for (int r = 0; r < 2; ++r) {
      const char* base = r ? pb : pa;
      unsigned long long q0 = ld_u64_agt(base);
      unsigned long long q1 = ld_u64_agt(base + 8);
      unsigned long long q2 = ld_u64_agt(base + 16);
      unsigned long long q3 = ld_u64_agt(base + 24);
      d[2 * r][0] = (unsigned)q0; d[2 * r][1] = (unsigned)(q0 >> 32);
      d[2 * r][2] = (unsigned)q1; d[2 * r][3] = (unsigned)(q1 >> 32);
      d[2 * r + 1][0] = (unsigned)q2; d[2 * r + 1][1] = (unsigned)(q2 >> 32);
      d[2 * r + 1][2] = (unsigned)q3; d[2 * r + 1][3] = (unsigned)(q3 >> 32);
    }
  }
}

// R5 sc1 flag barrier, verbatim (proven R5/R4). Entry __syncthreads drains
// each wave's stores (vmcnt) before the leader publishes its epoch.
__device__ __forceinline__ void gbar(unsigned* flags, int hb, unsigned& epoch) {
  ++epoch;
  __syncthreads();
  if (threadIdx.x < 64) {
    if (threadIdx.x == 0) st_u32_agt(flags + hb, epoch);
    const unsigned* fp = flags + (threadIdx.x & 31);
    for (;;) {
      unsigned v = ld_u32_agt(fp);
      if (__all((int)(v - epoch) >= 0)) break;
      __builtin_amdgcn_s_sleep(1);
    }
  }
  __syncthreads();
}

// ---- bf16 split helpers (R5 verbatim) ----
__device__ __forceinline__ unsigned short f2bf(float f) {
  union { float f; unsigned u; } v; v.f = f;
  unsigned r = v.u + 0x7fffu + ((v.u >> 16) & 1u);
  return (unsigned short)(r >> 16);
}
__device__ __forceinline__ float bf2f(unsigned short u) {
  union { float f; unsigned u; } v; v.u = ((unsigned)u) << 16; return v.f;
}
__device__ __forceinline__ void split2(float f, unsigned short& hi, unsigned short& lo) {
  hi = f2bf(f);
  lo = f2bf(f - bf2f(hi));
}
__device__ __forceinline__ void load_wfrag(const float* __restrict__ p, short8& h, short8& l) {
#pragma unroll
  for (int j = 0; j < 8; ++j) {
    unsigned short a, b2; split2(p[j], a, b2);
    h[j] = (short)a; l[j] = (short)b2;
  }
}
__device__ __forceinline__ void load_frags_single(const float* __restrict__ W, int w, int hb, int lane,
                                                  short8 (&fh)[4][4], short8 (&fl)[4][4]) {
  const int ln = lane & 15, lq = lane >> 4;
#pragma unroll
  for (int cc = 0; cc < 4; ++cc) {
    const int k = (w * 4 + cc) * 32 + lq * 8;
#pragma unroll
    for (int g = 0; g < 4; ++g)
      load_wfrag(W + (size_t)(g * NH + hb * 16 + ln) * NH + k, fh[cc][g], fl[cc][g]);
  }
}
__device__ __forceinline__ void load_frags_concat(const float* __restrict__ Wa, const float* __restrict__ Wb,
                                                  int w, int hb, int lane,
                                                  short8 (&fh)[8][4], short8 (&fl)[8][4]) {
  const int ln = lane & 15, lq = lane >> 4;
#pragma unroll
  for (int cc = 0; cc < 8; ++cc) {
    const int k = (w * 8 + cc) * 32 + lq * 8;
    const float* W = (k < 512) ? Wa : Wb;
    const int kk = (k < 512) ? k : k - 512;
#pragma unroll
    for (int g = 0; g < 4; ++g)
      load_wfrag(W + (size_t)(g * NH + hb * 16 + ln) * NH + kk, fh[cc][g], fl[cc][g]);
  }
}

// one packed chunk (2 uint4v) -> bf16x3 MFMA into acc
__device__ __forceinline__ void consume2(const uint4v& a, const uint4v& b,
                                         const short8 (&wh)[4], const short8 (&wl)[4],
                                         float4v (&acc)[4]) {
  unsigned x0 = a[0], x1 = a[1], x2 = a[2], x3 = a[3];
  unsigned x4 = b[0], x5 = b[1], x6 = b[2], x7 = b[3];
  union U { unsigned u[4]; short8 s; } A, L;
  A.u[0] = (x0 & 0xffffu) | (x1 << 16);
  A.u[1] = (x2 & 0xffffu) | (x3 << 16);
  A.u[2] = (x4 & 0xffffu) | (x5 << 16);
  A.u[3] = (x6 & 0xffffu) | (x7 << 16);
  L.u[0] = (x0 >> 16) | (x1 & 0xffff0000u);
  L.u[1] = (x2 >> 16) | (x3 & 0xffff0000u);
  L.u[2] = (x4 >> 16) | (x5 & 0xffff0000u);
  L.u[3] = (x6 >> 16) | (x7 & 0xffff0000u);
  const short8 ah = A.s, al = L.s;
#pragma unroll
  for (int g = 0; g < 4; ++g) {
    acc[g] = __builtin_amdgcn_mfma_f32_16x16x32_bf16(ah, wh[g], acc[g], 0, 0, 0);
    acc[g] = __builtin_amdgcn_mfma_f32_16x16x32_bf16(ah, wl[g], acc[g], 0, 0, 0);
    acc[g] = __builtin_amdgcn_mfma_f32_16x16x32_bf16(al, wh[g], acc[g], 0, 0, 0);
  }
}
__device__ __forceinline__ void write_red(float* __restrict__ red, int w, int lane, const float4v (&acc)[4]) {
  const int ln = lane & 15, lq = lane >> 4;
#pragma unroll
  for (int g = 0; g < 4; ++g)
#pragma unroll
    for (int r = 0; r < 4; ++r)
      red[((w * 4 + g) * 16 + (lq * 4 + r)) * 16 + ln] = acc[g][r];
}
__device__ __forceinline__ void store_h(bool fast, char* __restrict__ plane, int b, int hid, float h) {
  unsigned short hi, lo; split2(h, hi, lo);
  const size_t off = (size_t)(hid >> 5) * CHUNK_BYTES + (size_t)b * 128 + (size_t)(hid & 31) * 4;
  unsigned* p = (unsigned*)(plane + off);
  unsigned v = (unsigned)hi | ((unsigned)lo << 16);
  if (fast) __hip_atomic_store(p, v, __ATOMIC_RELAXED, SCOPE_WG);   // plain -> XCD L2
  else      st_u32_agt(p, v);                                       // sc1
}
__device__ __forceinline__ void st_f32s(bool fast, float* p, float v) {
  if (fast) __hip_atomic_store(p, v, __ATOMIC_RELAXED, SCOPE_WG);
  else      __hip_atomic_store(p, v, __ATOMIC_RELAXED, SCOPE_AGT);
}
__device__ __forceinline__ float sigf(float v) { return 1.f / (1.f + __expf(-v)); }

extern "C" __global__ __launch_bounds__(NTHR, 1)
void lstm_ae_kernel(const float* __restrict__ x,
                    const float* __restrict__ eWih0, const float* __restrict__ eWhh0, const float* __restrict__ eb0,
                    const float* __restrict__ eWih1, const float* __restrict__ eWhh1, const float* __restrict__ eb1,
                    const float* __restrict__ dWih0, const float* __restrict__ dWhh0, const float* __restrict__ db0,
                    const float* __restrict__ dWih1, const float* __restrict__ dWhh1, const float* __restrict__ db1,
                    const float* __restrict__ Wout,  const float* __restrict__ bout,
                    float* __restrict__ out, char* __restrict__ wsB) {
  __shared__ float red0[4 * 4 * 16 * 16];  // 16KB
  __shared__ float red1[4 * 4 * 16 * 16];  // 16KB
  __shared__ unsigned sh_slot;

  unsigned* xcnt   = (unsigned*)(wsB + 9216);   // [8]
  unsigned* gflags = (unsigned*)(wsB + 10240);  // [256]

  const int tid = threadIdx.x;
  const int lane = tid & 63;
  const int w = tid >> 6;

  // ---- roster: group := physical XCD, hid-block := arrival slot ----
  const unsigned xcc = (unsigned)__builtin_amdgcn_s_getreg(63508) & 15u;  // hwreg(XCC_ID=20,0,32)
  if (tid == 0)
    sh_slot = __hip_atomic_fetch_add(xcnt + (xcc & 7u), 1u, __ATOMIC_RELAXED, SCOPE_AGT);
  __syncthreads();
  const unsigned slot = sh_slot;
  // one-time device-wide barrier (sc1 flag array over all 256 WGs)
  if (tid == 0) st_u32_agt(gflags + blockIdx.x, 1u);
  if (tid < 64) {
    for (;;) {
      int ok = 1;
#pragma unroll
      for (int j = 0; j < 4; ++j) ok &= (ld_u32_agt(gflags + lane * 4 + j) != 0u);
      if (__all(ok)) break;
      __builtin_amdgcn_s_sleep(1);
    }
  }
  __syncthreads();
  bool good = (slot < GWG);
#pragma unroll
  for (int k = 0; k < 8; ++k) good = good && (ld_u32_agt(xcnt + k) == GWG);

  const int grp = good ? (int)(xcc & 7u) : (blockIdx.x & 7);
  const int hb  = good ? (int)slot        : (blockIdx.x >> 3);
  const bool fast = good;

  unsigned* flags = (unsigned*)(wsB + (size_t)grp * 1024);
  unsigned epoch = 0;

  const int b0 = grp * 16;
  const int ln = lane & 15, lq = lane >> 4;
  const int aoff = (b0 + ln) * 128 + lq * 32;
  const int bi = tid >> 4, hi_ = tid & 15;
  const int b = b0 + bi, hid = hb * 16 + hi_;
  const float4v zacc = {0.f, 0.f, 0.f, 0.f};

  // ---- prologue ----
  store_h(fast, AH_PLANE(wsB, 0, 1), b, hid, 0.f);
  store_h(fast, AH_PLANE(wsB, 1, 1), b, hid, 0.f);
  float c0 = 0.f, c1 = 0.f, c2 = 0.f, c3 = 0.f;
  const float eb0v[4] = {eb0[hid], eb0[NH + hid], eb0[2 * NH + hid], eb0[3 * NH + hid]};
  const float eb1v[4] = {eb1[hid], eb1[NH + hid], eb1[2 * NH + hid], eb1[3 * NH + hid]};
  const float db1v[4] = {db1[hid], db1[NH + hid], db1[2 * NH + hid], db1[3 * NH + hid]};

  short8 w0h[4][4], w0l[4][4];
  short8 w1h[8][4], w1l[8][4];
  load_frags_single(eWhh0, w, hb, lane, w0h, w0l);
  load_frags_concat(eWih1, eWhh1, w, hb, lane, w1h, w1l);
  gbar(flags, hb, epoch);

  float h0fin = 0.f, h1fin = 0.f;

  // ============ encoder: interval i = enc0(t=i) || enc1(te=i-1) ============
  for (int i = 0; i <= NT; ++i) {
    const int pw = i & 1, pr = pw ^ 1;
    const int te = i - 1;
    const int pA = te & 1, pB = pA ^ 1;
    const char* p0 = AH_PLANE(wsB, 0, pr);
    const char* p1 = (w < 2) ? AH_PLANE(wsB, 0, pA) : AH_PLANE(wsB, 1, pB);
    const int c1i = (w < 2) ? w * 8 : (w - 2) * 8;
    float4v acc0[4] = {zacc, zacc, zacc, zacc};
    float4v acc1[4] = {zacc, zacc, zacc, zacc};
    uint4v d[4];

    loadpair(fast, p0 + (size_t)(w * 4 + 0) * CHUNK_BYTES + aoff,
                   p0 + (size_t)(w * 4 + 1) * CHUNK_BYTES + aoff, d);
    consume2(d[0], d[1], w0h[0], w0l[0], acc0);
    consume2(d[2], d[3], w0h[1], w0l[1], acc0);
    loadpair(fast, p0 + (size_t)(w * 4 + 2) * CHUNK_BYTES + aoff,
                   p0 + (size_t)(w * 4 + 3) * CHUNK_BYTES + aoff, d);
    consume2(d[0], d[1], w0h[2], w0l[2], acc0);
    consume2(d[2], d[3], w0h[3], w0l[3], acc0);
    write_red(red0, w, lane, acc0);
#pragma unroll
    for (int pp = 0; pp < 4; ++pp) {
      loadpair(fast, p1 + (size_t)(c1i + 2 * pp) * CHUNK_BYTES + aoff,
                     p1 + (size_t)(c1i + 2 * pp + 1) * CHUNK_BYTES + aoff, d);
      consume2(d[0], d[1], w1h[2 * pp], w1l[2 * pp], acc1);
      consume2(d[2], d[3], w1h[2 * pp + 1], w1l[2 * pp + 1], acc1);
    }
    write_red(red1, w, lane, acc1);
    __syncthreads();

    if (i < NT) {  // enc0 epilogue (+ exact fp32 x-term)
      float s[4];
#pragma unroll
      for (int g = 0; g < 4; ++g) {
        float v = eb0v[g];
#pragma unroll
        for (int ww = 0; ww < 4; ++ww) v += red0[((ww * 4 + g) * 16 + bi) * 16 + hi_];
        s[g] = v;
      }
      const float* xr = x + ((size_t)b * NT + i) * ND;
      float xv[16];
#pragma unroll
      for (int j = 0; j < 16; ++j) xv[j] = xr[j];
#pragma unroll
      for (int g = 0; g < 4; ++g) {
        const float* wr = eWih0 + (size_t)(g * NH + hid) * ND;
        float v = 0.f;
#pragma unroll
        for (int j = 0; j < 16; ++j) v += xv[j] * wr[j];
        s[g] += v;
      }
      float ig = sigf(s[0]), fg = sigf(s[1]), gg = tanhf(s[2]), og = sigf(s[3]);
      c0 = fg * c0 + ig * gg;
      float h = og * tanhf(c0);
      store_h(fast, AH_PLANE(wsB, 0, pw), b, hid, h);
      if (i == NT - 1) h0fin = h;
    }
    if (i >= 1) {  // enc1 epilogue
      float s[4];
#pragma unroll
      for (int g = 0; g < 4; ++g) {
        float v = eb1v[g];
#pragma unroll
        for (int ww = 0; ww < 4; ++ww) v += red1[((ww * 4 + g) * 16 + bi) * 16 + hi_];
        s[g] = v;
      }
      float ig = sigf(s[0]), fg = sigf(s[1]), gg = tanhf(s[2]), og = sigf(s[3]);
      c1 = fg * c1 + ig * gg;
      float h = og * tanhf(c1);
      store_h(fast, AH_PLANE(wsB, 1, pA), b, hid, h);
      if (te == NT - 1) h1fin = h;
    }
    gbar(flags, hb, epoch);
  }

  // ============ transition ============
  out[(size_t)NB * NT * ND + (size_t)b * NH + hid] = h1fin;  // encoding
  c2 = c0; c3 = c1;
  store_h(fast, AH_PLANE(wsB, 2, 1), b, hid, h0fin);
  store_h(fast, AH_PLANE(wsB, 3, 1), b, hid, h1fin);

  float Gbreg[4];
  load_frags_single(dWih0, w, hb, lane, w0h, w0l);
  {  // Gb = db0 + encoding @ dWih0^T ; A = h1 plane par1
    const char* ph = AH_PLANE(wsB, 1, 1);
    float4v acc[4] = {zacc, zacc, zacc, zacc};
    uint4v d[4];
    loadpair(fast, ph + (size_t)(w * 4 + 0) * CHUNK_BYTES + aoff,
                   ph + (size_t)(w * 4 + 1) * CHUNK_BYTES + aoff, d);
    consume2(d[0], d[1], w0h[0], w0l[0], acc);
    consume2(d[2], d[3], w0h[1], w0l[1], acc);
    loadpair(fast, ph + (size_t)(w * 4 + 2) * CHUNK_BYTES + aoff,
                   ph + (size_t)(w * 4 + 3) * CHUNK_BYTES + aoff, d);
    consume2(d[0], d[1], w0h[2], w0l[2], acc);
    consume2(d[2], d[3], w0h[3], w0l[3], acc);
    write_red(red0, w, lane, acc);
    __syncthreads();
#pragma unroll
    for (int g = 0; g < 4; ++g) {
      float v = db0[g * NH + hid];
#pragma unroll
      for (int ww = 0; ww < 4; ++ww) v += red0[((ww * 4 + g) * 16 + bi) * 16 + hi_];
      Gbreg[g] = v;
    }
  }
  load_frags_single(dWhh0, w, hb, lane, w0h, w0l);
  load_frags_concat(dWih1, dWhh1, w, hb, lane, w1h, w1l);
  gbar(flags, hb, epoch);

  // ==== decoder: interval i = proj(tp=i-2) || dec0(t=i) || dec1(te=i-1) ====
  const int idxA = hb * 8 + w * 2, idxB = idxA + 1;
  const int pbA = b0 + (idxA >> 4), pdA = idxA & 15;
  const int pbB = b0 + (idxB >> 4), pdB = idxB & 15;

  for (int i = 0; i <= NT + 1; ++i) {
    const int pw = i & 1, pr = pw ^ 1;
    const int te = i - 1, tp = i - 2;
    const int pA = te & 1, pB = pA ^ 1;
    const char* p0 = AH_PLANE(wsB, 2, pr);
    const char* p1 = (w < 2) ? AH_PLANE(wsB, 2, pA) : AH_PLANE(wsB, 3, pB);
    const int c1i = (w < 2) ? w * 8 : (w - 2) * 8;
    const float* H3 = H3F_PTR(wsB, tp & 1);
    float4v acc0[4] = {zacc, zacc, zacc, zacc};
    float4v acc1[4] = {zacc, zacc, zacc, zacc};
    uint4v d[4];

    loadpair(fast, p0 + (size_t)(w * 4 + 0) * CHUNK_BYTES + aoff,
                   p0 + (size_t)(w * 4 + 1) * CHUNK_BYTES + aoff, d);
    consume2(d[0], d[1], w0h[0], w0l[0], acc0);
    consume2(d[2], d[3], w0h[1], w0l[1], acc0);
    loadpair(fast, p0 + (size_t)(w * 4 + 2) * CHUNK_BYTES + aoff,
                   p0 + (size_t)(w * 4 + 3) * CHUNK_BYTES + aoff, d);
    consume2(d[0], d[1], w0h[2], w0l[2], acc0);
    consume2(d[2], d[3], w0h[3], w0l[3], acc0);
    write_red(red0, w, lane, acc0);
#pragma unroll
    for (int pp = 0; pp < 4; ++pp) {
      loadpair(fast, p1 + (size_t)(c1i + 2 * pp) * CHUNK_BYTES + aoff,
                     p1 + (size_t)(c1i + 2 * pp + 1) * CHUNK_BYTES + aoff, d);
      consume2(d[0], d[1], w1h[2 * pp], w1l[2 * pp], acc1);
      consume2(d[2], d[3], w1h[2 * pp + 1], w1l[2 * pp + 1], acc1);
    }
    write_red(red1, w, lane, acc1);
    // projection rows for tp (read-after-barrier state)
    uint4v dp[4];
    loadpair(fast, (const char*)(H3 + (size_t)pbA * NH) + (size_t)lane * 32,
                   (const char*)(H3 + (size_t)pbB * NH) + (size_t)lane * 32, dp);
    __syncthreads();

    if (i >= 2) {  // projection epilogue
#pragma unroll
      for (int rep = 0; rep < 2; ++rep) {
        union PU { uint4v u; float f[4]; } u0, u1;
        u0.u = dp[2 * rep]; u1.u = dp[2 * rep + 1];
        const int pd = rep ? pdB : pdA;
        const float* wr = Wout + (size_t)pd * NH + lane * 8;
        float ssum = u0.f[0] * wr[0] + u0.f[1] * wr[1] + u0.f[2] * wr[2] + u0.f[3] * wr[3]
                   + u1.f[0] * wr[4] + u1.f[1] * wr[5] + u1.f[2] * wr[6] + u1.f[3] * wr[7];
#pragma unroll
        for (int off = 32; off >= 1; off >>= 1) ssum += __shfl_xor(ssum, off, 64);
        if (lane == 0)
          out[((size_t)(rep ? pbB : pbA) * NT + tp) * ND + pd] = ssum + bout[pd];
      }
    }
    if (i < NT) {  // dec0 epilogue
      float s[4];
#pragma unroll
      for (int g = 0; g < 4; ++g) {
        float v = Gbreg[g];
#pragma unroll
        for (int ww = 0; ww < 4; ++ww) v += red0[((ww * 4 + g) * 16 + bi) * 16 + hi_];
        s[g] = v;
      }
      float ig = sigf(s[0]), fg = sigf(s[1]), gg = tanhf(s[2]), og = sigf(s[3]);
      c2 = fg * c2 + ig * gg;
      float h = og * tanhf(c2);
      store_h(fast, AH_PLANE(wsB, 2, pw), b, hid, h);
    }
    if (i >= 1 && i <= NT) {  // dec1 epilogue
      float s[4];
#pragma unroll
      for (int g = 0; g < 4; ++g) {
        float v = db1v[g];
#pragma unroll
        for (int ww = 0; ww < 4; ++ww) v += red1[((ww * 4 + g) * 16 + bi) * 16 + hi_];
        s[g] = v;
      }
      float ig = sigf(s[0]), fg = sigf(s[1]), gg = tanhf(s[2]), og = sigf(s[3]);
      c3 = fg * c3 + ig * gg;
      float h = og * tanhf(c3);
      store_h(fast, AH_PLANE(wsB, 3, pA), b, hid, h);
      st_f32s(fast, H3F_PTR(wsB, pA) + (size_t)b * NH + hid, h);
    }
    if (i != NT + 1) gbar(flags, hb, epoch);
  }
}

extern "C" void kernel_launch(void* const* d_in, const int* in_sizes, int n_in,
                              void* d_out, int out_size, void* d_ws, size_t ws_size,
                              hipStream_t stream) {
  const float* xp    = (const float*)d_in[0];
  const float* eWih0 = (const float*)d_in[1];
  const float* eWhh0 = (const float*)d_in[2];
  const float* eb0   = (const float*)d_in[3];
  const float* eWih1 = (const float*)d_in[4];
  const float* eWhh1 = (const float*)d_in[5];
  const float* eb1   = (const float*)d_in[6];
  const float* dWih0 = (const float*)d_in[7];
  const float* dWhh0 = (const float*)d_in[8];
  const float* db0   = (const float*)d_in[9];
  const float* dWih1 = (const float*)d_in[10];
  const float* dWhh1 = (const float*)d_in[11];
  const float* db1   = (const float*)d_in[12];
  const float* Wout  = (const float*)d_in[13];
  const float* bout  = (const float*)d_in[14];

  hipMemsetAsync(d_ws, 0, BAR_BYTES, stream);  // flags + roster + gflags
  lstm_ae_kernel<<<NWG, NTHR, 0, stream>>>(
      xp, eWih0, eWhh0, eb0, eWih1, eWhh1, eb1,
      dWih0, dWhh0, db0, dWih1, dWhh1, db1, Wout, bout,
      (float*)d_out, (char*)d_ws);
}